// Round 1
// baseline (34719.296 us; speedup 1.0000x reference)
//
#include <hip/hip_runtime.h>
#include <math.h>

#define NPROD 50
#define DXF 32
#define DZF 20
#define WUW 128
#define LXD 16
#define LZD 16

__device__ __forceinline__ float elu_f(float x) {
    return x > 0.0f ? x : expm1f(x);
}

// [50][IN] (LDS) @ [IN][OUT] (global) -> [50][OUT] (LDS); 2 rows x 4 cols per item
template<int IN, int OUT, bool ACT>
__device__ __forceinline__ void dense50(const float* __restrict__ in_lds,
                                        const float* __restrict__ Wg,
                                        float* __restrict__ out_lds)
{
    const int tid = threadIdx.x;
    constexpr int CQ = OUT / 4;
    const float4* __restrict__ W4 = (const float4*)Wg;
    for (int item = tid; item < 25 * CQ; item += 256) {
        const int rp = item / CQ;
        const int cq = item % CQ;
        const int r0 = rp, r1 = rp + 25;
        float4 a0 = {0.f,0.f,0.f,0.f}, a1 = {0.f,0.f,0.f,0.f};
        for (int k = 0; k < IN; ++k) {
            const float4 w = W4[k * CQ + cq];
            const float x0 = in_lds[r0 * IN + k];
            const float x1 = in_lds[r1 * IN + k];
            a0.x = fmaf(x0, w.x, a0.x); a0.y = fmaf(x0, w.y, a0.y);
            a0.z = fmaf(x0, w.z, a0.z); a0.w = fmaf(x0, w.w, a0.w);
            a1.x = fmaf(x1, w.x, a1.x); a1.y = fmaf(x1, w.y, a1.y);
            a1.z = fmaf(x1, w.z, a1.z); a1.w = fmaf(x1, w.w, a1.w);
        }
        if (ACT) {
            a0.x = elu_f(a0.x); a0.y = elu_f(a0.y); a0.z = elu_f(a0.z); a0.w = elu_f(a0.w);
            a1.x = elu_f(a1.x); a1.y = elu_f(a1.y); a1.z = elu_f(a1.z); a1.w = elu_f(a1.w);
        }
        ((float4*)out_lds)[r0 * CQ + cq] = a0;
        ((float4*)out_lds)[r1 * CQ + cq] = a1;
    }
}

// [50][128] (LDS) @ [128][128] (global) -> [50][128] (LDS); 4 rows x 4 cols per item
template<bool ACT>
__device__ __forceinline__ void dense128(const float* __restrict__ in_lds,
                                         const float* __restrict__ Wg,
                                         float* __restrict__ out_lds)
{
    const int tid = threadIdx.x;
    const float4* __restrict__ W4 = (const float4*)Wg;
    for (int item = tid; item < 13 * 32; item += 256) {
        const int rg = item >> 5;
        const int cq = item & 31;
        int r[4];
        #pragma unroll
        for (int t = 0; t < 4; ++t) r[t] = min(rg * 4 + t, NPROD - 1);
        float4 a[4];
        #pragma unroll
        for (int t = 0; t < 4; ++t) a[t] = make_float4(0.f, 0.f, 0.f, 0.f);
        for (int k = 0; k < 128; ++k) {
            const float4 w = W4[k * 32 + cq];
            #pragma unroll
            for (int t = 0; t < 4; ++t) {
                const float x = in_lds[r[t] * 128 + k];
                a[t].x = fmaf(x, w.x, a[t].x); a[t].y = fmaf(x, w.y, a[t].y);
                a[t].z = fmaf(x, w.z, a[t].z); a[t].w = fmaf(x, w.w, a[t].w);
            }
        }
        #pragma unroll
        for (int t = 0; t < 4; ++t) {
            const int row = rg * 4 + t;
            if (row < NPROD) {
                float4 o = a[t];
                if (ACT) { o.x = elu_f(o.x); o.y = elu_f(o.y); o.z = elu_f(o.z); o.w = elu_f(o.w); }
                ((float4*)out_lds)[row * 32 + cq] = o;
            }
        }
    }
}

// u0 = elu(Xb@Wu0[0:32] + Xi@Wu0[32:48] + preZ_j)
__device__ __forceinline__ void dense_u0(const float* __restrict__ sXb,
                                         const float* __restrict__ sXi,
                                         const float* __restrict__ preZ_j,
                                         const float* __restrict__ Wu0,
                                         float* __restrict__ out_lds)
{
    const int tid = threadIdx.x;
    const float4* __restrict__ W4 = (const float4*)Wu0;
    const float4* __restrict__ PZ4 = (const float4*)preZ_j;
    for (int item = tid; item < 13 * 32; item += 256) {
        const int rg = item >> 5;
        const int cq = item & 31;
        int r[4];
        #pragma unroll
        for (int t = 0; t < 4; ++t) r[t] = min(rg * 4 + t, NPROD - 1);
        const float4 pz = PZ4[cq];
        float4 a[4];
        #pragma unroll
        for (int t = 0; t < 4; ++t) a[t] = pz;
        for (int k = 0; k < DXF; ++k) {
            const float4 w = W4[k * 32 + cq];
            #pragma unroll
            for (int t = 0; t < 4; ++t) {
                const float x = sXb[r[t] * DXF + k];
                a[t].x = fmaf(x, w.x, a[t].x); a[t].y = fmaf(x, w.y, a[t].y);
                a[t].z = fmaf(x, w.z, a[t].z); a[t].w = fmaf(x, w.w, a[t].w);
            }
        }
        for (int k = 0; k < LXD; ++k) {
            const float4 w = W4[(DXF + k) * 32 + cq];
            #pragma unroll
            for (int t = 0; t < 4; ++t) {
                const float x = sXi[r[t] * LXD + k];
                a[t].x = fmaf(x, w.x, a[t].x); a[t].y = fmaf(x, w.y, a[t].y);
                a[t].z = fmaf(x, w.z, a[t].z); a[t].w = fmaf(x, w.w, a[t].w);
            }
        }
        #pragma unroll
        for (int t = 0; t < 4; ++t) {
            const int row = rg * 4 + t;
            if (row < NPROD) {
                float4 o = a[t];
                o.x = elu_f(o.x); o.y = elu_f(o.y); o.z = elu_f(o.z); o.w = elu_f(o.w);
                ((float4*)out_lds)[row * 32 + cq] = o;
            }
        }
    }
}

__global__ __launch_bounds__(256, 2) void rum_fused(
    const float* __restrict__ X, const float* __restrict__ Z,
    const float* __restrict__ Wx0, const float* __restrict__ Wx,
    const float* __restrict__ Wlx, const float* __restrict__ Wz0,
    const float* __restrict__ Wz, const float* __restrict__ Wlz,
    const float* __restrict__ Wu0, const float* __restrict__ Wu,
    const float* __restrict__ Wlast, float* __restrict__ out)
{
    __shared__ __align__(16) float sBufA[NPROD * WUW];   // 25.6 KB
    __shared__ __align__(16) float sBufB[NPROD * WUW];   // 25.6 KB
    __shared__ __align__(16) float sXb[NPROD * DXF];     // 6.4 KB
    __shared__ __align__(16) float sXi[NPROD * LXD];     // 3.2 KB
    __shared__ __align__(16) float sPreZ[3 * WUW];       // 1.5 KB

    const int b = blockIdx.x;
    const int tid = threadIdx.x;

    // Z-phase scratch aliased into sBufA (freed before X-branch uses sBufA)
    float* zsm = sBufA;          // [0:20)   Z row
    float* zh0 = sBufA + 64;     // [64:256) 3x64
    float* zh1 = sBufA + 256;    // [256:448)
    float* zjd = sBufA + 448;    // [448:496) Zj 3x16

    {
        const float* Xg = X + (size_t)b * (NPROD * DXF);
        for (int idx = tid; idx < NPROD * DXF; idx += 256) sXb[idx] = Xg[idx];
        const float* Zg = Z + (size_t)b * DZF;
        if (tid < DZF) zsm[tid] = Zg[tid];
    }
    __syncthreads();

    // ---- Z branch: 3 heterogeneities in parallel (threads 0..191) ----
    const int zj = tid >> 6;
    const int zc = tid & 63;
    if (zj < 3) {
        const float* w = Wz0 + zj * (DZF * 64);
        float s = 0.f;
        for (int k = 0; k < DZF; ++k) s = fmaf(zsm[k], w[k * 64 + zc], s);
        zh0[zj * 64 + zc] = elu_f(s);
    }
    __syncthreads();
    if (zj < 3) {
        const float* w = Wz + (zj * 2 + 0) * 4096;
        float s = 0.f;
        for (int k = 0; k < 64; ++k) s = fmaf(zh0[zj * 64 + k], w[k * 64 + zc], s);
        zh1[zj * 64 + zc] = elu_f(s);
    }
    __syncthreads();
    if (zj < 3) {
        const float* w = Wz + (zj * 2 + 1) * 4096;
        float s = 0.f;
        for (int k = 0; k < 64; ++k) s = fmaf(zh1[zj * 64 + k], w[k * 64 + zc], s);
        zh0[zj * 64 + zc] = elu_f(s);
    }
    __syncthreads();
    if (tid < 48) {  // Zj = h @ Wlz[j]  (linear)
        const int j = tid >> 4, c = tid & 15;
        const float* w = Wlz + j * (64 * LZD);
        float s = 0.f;
        for (int k = 0; k < 64; ++k) s = fmaf(zh0[j * 64 + k], w[k * LZD + c], s);
        zjd[j * LZD + c] = s;
    }
    __syncthreads();
    // preZ[j][c] = Zj[j]@Wu0[48:64] + Z@Wu0[64:84]
    for (int idx = tid; idx < 3 * WUW; idx += 256) {
        const int j = idx >> 7, c = idx & 127;
        float s = 0.f;
        for (int k = 0; k < LZD; ++k) s = fmaf(zjd[j * LZD + k], Wu0[(DXF + LXD + k) * WUW + c], s);
        for (int k = 0; k < DZF; ++k) s = fmaf(zsm[k], Wu0[(DXF + LXD + LZD + k) * WUW + c], s);
        sPreZ[idx] = s;
    }
    __syncthreads();

    float accv = 0.f;
    const float inv_norm = 1.0f / (1.0f + 1e-6f * (float)NPROD);

    for (int i = 0; i < 3; ++i) {
        // ---- X branch for heterogeneity i ----
        dense50<DXF, 64, true>(sXb, Wx0 + i * (DXF * 64), sBufA);
        __syncthreads();
        dense50<64, 64, true>(sBufA, Wx + (i * 2 + 0) * 4096, sBufB);
        __syncthreads();
        dense50<64, 64, true>(sBufB, Wx + (i * 2 + 1) * 4096, sBufA);
        __syncthreads();
        dense50<64, LXD, false>(sBufA, Wlx + 2 * (64 * LXD), sXi);  // leaked-k bug: Wlx[2] for all i
        __syncthreads();

        for (int j = 0; j < 3; ++j) {
            dense_u0(sXb, sXi, sPreZ + j * WUW, Wu0, sBufA);
            __syncthreads();
            dense128<true>(sBufA, Wu, sBufB);
            __syncthreads();
            dense128<true>(sBufB, Wu + 16384, sBufA);
            __syncthreads();
            // score + softmax entirely in wave 0
            if (tid < 64) {
                float sc = -3.0e38f;
                if (tid < NPROD) {
                    float s = 0.f;
                    for (int k = 0; k < WUW; ++k) s = fmaf(sBufA[tid * WUW + k], Wlast[k], s);
                    sc = s;
                }
                float m = sc;
                #pragma unroll
                for (int off = 32; off > 0; off >>= 1) m = fmaxf(m, __shfl_xor(m, off));
                float e = (tid < NPROD) ? expf(sc - m) : 0.f;
                float ssum = e;
                #pragma unroll
                for (int off = 32; off > 0; off >>= 1) ssum += __shfl_xor(ssum, off);
                if (tid < NPROD) accv += (1e-6f + e / ssum) * inv_norm;
            }
            __syncthreads();
        }
    }
    if (tid < NPROD) out[(size_t)b * NPROD + tid] = accv * (1.0f / 9.0f);
}

extern "C" void kernel_launch(void* const* d_in, const int* in_sizes, int n_in,
                              void* d_out, int out_size, void* d_ws, size_t ws_size,
                              hipStream_t stream) {
    const float* X     = (const float*)d_in[0];
    const float* Z     = (const float*)d_in[1];
    const float* Wx0   = (const float*)d_in[2];
    const float* Wx    = (const float*)d_in[3];
    const float* Wlx   = (const float*)d_in[4];
    const float* Wz0   = (const float*)d_in[5];
    const float* Wz    = (const float*)d_in[6];
    const float* Wlz   = (const float*)d_in[7];
    const float* Wu0   = (const float*)d_in[8];
    const float* Wu    = (const float*)d_in[9];
    const float* Wlast = (const float*)d_in[10];
    float* out = (float*)d_out;

    rum_fused<<<dim3(8192), dim3(256), 0, stream>>>(
        X, Z, Wx0, Wx, Wlx, Wz0, Wz, Wlz, Wu0, Wu, Wlast, out);
}

// Round 2
// 2000.908 us; speedup vs baseline: 17.3518x; 17.3518x over previous
//
#include <hip/hip_runtime.h>
#include <math.h>

#define NPROD 50
#define DXF 32
#define DZF 20
#define WUW 128
#define LXD 16
#define LZD 16

// ---------------- common helpers ----------------
typedef __attribute__((ext_vector_type(8))) short short8;
typedef __attribute__((ext_vector_type(4))) float float4_;

__device__ __forceinline__ float elu_f(float x) {
    return x > 0.0f ? x : expm1f(x);
}
__device__ __forceinline__ short f2bf(float x) {
    unsigned u = __builtin_bit_cast(unsigned, x);
    u += 0x7fffu + ((u >> 16) & 1u);        // RNE
    return (short)(u >> 16);
}
__device__ __forceinline__ float bf2f(short s) {
    unsigned u = ((unsigned)(unsigned short)s) << 16;
    return __builtin_bit_cast(float, u);
}
#define MFMA16(a, b, c) __builtin_amdgcn_mfma_f32_16x16x32_bf16((a), (b), (c), 0, 0, 0)

// ---------------- ws layout (element offsets) ----------------
// packed bf16 weights, B-operand layout: dst[((k>>3)*N + n)*8 + (k&7)]
#define PK_WX0   0        // [i][4][64][8]     3*2048
#define PK_WX    6144     // [i*2+l][8][64][8] 6*4096
#define PK_WLX2  30720    // [8][16][8]        1024
#define PK_WU0   31744    // [8][128][8]       8192  (K padded 48->64, zeros)
#define PK_WU    39936    // [l][16][128][8]   2*16384
#define PK_TOTAL 72704
#define PREZ_OFF_B  147456                 // bytes; [8192][3][128] f32
#define XI_OFF_B    (147456 + 12582912)    // bytes; [3][409600][16] bf16
#define WS_NEEDED   (XI_OFF_B + (size_t)3*409600*16*2)

// =====================================================================
// Kernel 1: pack fp32 weights -> bf16 B-operand layout in ws
// =====================================================================
__global__ void pack_weights(const float* __restrict__ Wx0, const float* __restrict__ Wx,
                             const float* __restrict__ Wlx, const float* __restrict__ Wu0,
                             const float* __restrict__ Wu, short* __restrict__ pk)
{
    int idx = blockIdx.x * 256 + threadIdx.x;
    if (idx >= PK_TOTAL) return;
    const float* src; int Kr, N, base, matsz;
    if (idx < PK_WX) { base = PK_WX0; matsz = 2048; Kr = 32; N = 64;
        int m = (idx - base) / matsz; src = Wx0 + m * (32 * 64); }
    else if (idx < PK_WLX2) { base = PK_WX; matsz = 4096; Kr = 64; N = 64;
        int m = (idx - base) / matsz; src = Wx + m * 4096; }
    else if (idx < PK_WU0) { base = PK_WLX2; matsz = 1024; Kr = 64; N = 16;
        src = Wlx + 2 * 1024; }  // leaked-k bug: Wlx[2] only
    else if (idx < PK_WU) { base = PK_WU0; matsz = 8192; Kr = 48; N = 128;
        src = Wu0; }
    else { base = PK_WU; matsz = 16384; Kr = 128; N = 128;
        int m = (idx - base) / matsz; src = Wu + m * 16384; }
    int e = (idx - base) % matsz;
    int j = e & 7, t = e >> 3;
    int n = t % N, kq = t / N;
    int k = kq * 8 + j;
    pk[idx] = (k < Kr) ? f2bf(src[k * N + n]) : (short)0;
}

// =====================================================================
// Kernel 2: Z-branch + preZ[b][j][:] = Zj@Wu0[48:64] + Z@Wu0[64:84]
// block = 4 customers x 64 cols
// =====================================================================
__global__ __launch_bounds__(256, 4) void z_prez(
    const float* __restrict__ Z, const float* __restrict__ Wz0,
    const float* __restrict__ Wz, const float* __restrict__ Wlz,
    const float* __restrict__ Wu0, float* __restrict__ preZ)
{
    __shared__ float sZ[4][DZF], sH0[4][64], sH1[4][64], sZj[4][LZD];
    const int tid = threadIdx.x;
    const int cu = tid >> 6, col = tid & 63;
    const int b0 = blockIdx.x * 4;
    if (tid < 80) sZ[tid / DZF][tid % DZF] = Z[(size_t)(b0 + tid / DZF) * DZF + tid % DZF];
    __syncthreads();
    for (int j = 0; j < 3; ++j) {
        { const float* w = Wz0 + j * (DZF * 64);
          float s = 0.f;
          for (int k = 0; k < DZF; ++k) s = fmaf(sZ[cu][k], w[k * 64 + col], s);
          sH0[cu][col] = elu_f(s); }
        __syncthreads();
        { const float* w = Wz + (j * 2 + 0) * 4096;
          float s = 0.f;
          for (int k = 0; k < 64; ++k) s = fmaf(sH0[cu][k], w[k * 64 + col], s);
          sH1[cu][col] = elu_f(s); }
        __syncthreads();
        { const float* w = Wz + (j * 2 + 1) * 4096;
          float s = 0.f;
          for (int k = 0; k < 64; ++k) s = fmaf(sH1[cu][k], w[k * 64 + col], s);
          sH0[cu][col] = elu_f(s); }
        __syncthreads();
        if (col < LZD) {
            const float* w = Wlz + j * (64 * LZD);
            float s = 0.f;
            for (int k = 0; k < 64; ++k) s = fmaf(sH0[cu][k], w[k * LZD + col], s);
            sZj[cu][col] = s;
        }
        __syncthreads();
        for (int half = 0; half < 2; ++half) {
            const int c = col + half * 64;
            float s = 0.f;
            for (int k = 0; k < LZD; ++k) s = fmaf(sZj[cu][k], Wu0[(48 + k) * WUW + c], s);
            for (int k = 0; k < DZF; ++k) s = fmaf(sZ[cu][k], Wu0[(64 + k) * WUW + c], s);
            preZ[((size_t)(b0 + cu) * 3 + j) * WUW + c] = s;
        }
        __syncthreads();
    }
}

// =====================================================================
// Kernel 3: X-branch MFMA. 128 rows/block over 409600 rows.
// XI[i][r][16] bf16 out. Weights (packed bf16) streamed from L2.
// =====================================================================
__global__ __launch_bounds__(256, 3) void x_branch(
    const float* __restrict__ X, const short* __restrict__ pk, short* __restrict__ XI)
{
    __shared__ __align__(16) short sA[128 * 40];   // X rows, stride 40
    __shared__ __align__(16) short sH0[128 * 72];  // stride 72
    __shared__ __align__(16) short sH1[128 * 72];

    const int tid = threadIdx.x;
    const int w = tid >> 6, lane = tid & 63;
    const int quad = lane >> 4, l15 = lane & 15;
    const long r0 = (long)blockIdx.x * 128;

    // stage X -> bf16 LDS
    for (int idx = tid; idx < 128 * 32; idx += 256) {
        int r = idx >> 5, c = idx & 31;
        sA[r * 40 + c] = f2bf(X[r0 * 32 + idx]);
    }
    __syncthreads();

    for (int i = 0; i < 3; ++i) {
        float4_ acc[2][4];
        // ---- l0: [128x32] @ [32x64] ----
        #pragma unroll
        for (int mi = 0; mi < 2; ++mi)
            #pragma unroll
            for (int ni = 0; ni < 4; ++ni) acc[mi][ni] = (float4_)0.f;
        {
            const short* B = pk + PK_WX0 + i * 2048;
            short8 a[2], bfr[4];
            #pragma unroll
            for (int mi = 0; mi < 2; ++mi) {
                int mt = w * 2 + mi;
                a[mi] = *(const short8*)(sA + (mt * 16 + l15) * 40 + quad * 8);
            }
            #pragma unroll
            for (int ni = 0; ni < 4; ++ni)
                bfr[ni] = *(const short8*)(B + (quad * 64 + ni * 16 + l15) * 8);
            #pragma unroll
            for (int mi = 0; mi < 2; ++mi)
                #pragma unroll
                for (int ni = 0; ni < 4; ++ni)
                    acc[mi][ni] = MFMA16(a[mi], bfr[ni], acc[mi][ni]);
        }
        #pragma unroll
        for (int mi = 0; mi < 2; ++mi)
            #pragma unroll
            for (int ni = 0; ni < 4; ++ni) {
                int row0 = (w * 2 + mi) * 16 + quad * 4;
                int c = ni * 16 + l15;
                #pragma unroll
                for (int r = 0; r < 4; ++r)
                    sH0[(row0 + r) * 72 + c] = f2bf(elu_f(acc[mi][ni][r]));
            }
        __syncthreads();

        // ---- l1, l2: [128x64] @ [64x64] ----
        for (int l = 0; l < 2; ++l) {
            const short* sIn = l == 0 ? sH0 : sH1;
            short* sOut = l == 0 ? sH1 : sH0;
            const short* B = pk + PK_WX + (i * 2 + l) * 4096;
            #pragma unroll
            for (int mi = 0; mi < 2; ++mi)
                #pragma unroll
                for (int ni = 0; ni < 4; ++ni) acc[mi][ni] = (float4_)0.f;
            #pragma unroll
            for (int ks = 0; ks < 2; ++ks) {
                short8 a[2], bfr[4];
                #pragma unroll
                for (int mi = 0; mi < 2; ++mi) {
                    int mt = w * 2 + mi;
                    a[mi] = *(const short8*)(sIn + (mt * 16 + l15) * 72 + ks * 32 + quad * 8);
                }
                #pragma unroll
                for (int ni = 0; ni < 4; ++ni)
                    bfr[ni] = *(const short8*)(B + ((ks * 4 + quad) * 64 + ni * 16 + l15) * 8);
                #pragma unroll
                for (int mi = 0; mi < 2; ++mi)
                    #pragma unroll
                    for (int ni = 0; ni < 4; ++ni)
                        acc[mi][ni] = MFMA16(a[mi], bfr[ni], acc[mi][ni]);
            }
            #pragma unroll
            for (int mi = 0; mi < 2; ++mi)
                #pragma unroll
                for (int ni = 0; ni < 4; ++ni) {
                    int row0 = (w * 2 + mi) * 16 + quad * 4;
                    int c = ni * 16 + l15;
                    #pragma unroll
                    for (int r = 0; r < 4; ++r)
                        sOut[(row0 + r) * 72 + c] = f2bf(elu_f(acc[mi][ni][r]));
                }
            __syncthreads();
        }

        // ---- ll: [128x64] @ [64x16], linear, direct global write ----
        {
            const short* B = pk + PK_WLX2;
            float4_ accl[2];
            accl[0] = (float4_)0.f; accl[1] = (float4_)0.f;
            #pragma unroll
            for (int ks = 0; ks < 2; ++ks) {
                short8 a[2], bfr;
                #pragma unroll
                for (int mi = 0; mi < 2; ++mi) {
                    int mt = w * 2 + mi;
                    a[mi] = *(const short8*)(sH0 + (mt * 16 + l15) * 72 + ks * 32 + quad * 8);
                }
                bfr = *(const short8*)(B + ((ks * 4 + quad) * 16 + l15) * 8);
                #pragma unroll
                for (int mi = 0; mi < 2; ++mi)
                    accl[mi] = MFMA16(a[mi], bfr, accl[mi]);
            }
            #pragma unroll
            for (int mi = 0; mi < 2; ++mi) {
                long row = r0 + (w * 2 + mi) * 16 + quad * 4;
                #pragma unroll
                for (int r = 0; r < 4; ++r)
                    XI[((long)i * 409600 + row + r) * 16 + l15] = f2bf(accl[mi][r]);
            }
        }
        __syncthreads();
    }
}

// =====================================================================
// Kernel 4: utility MLP, one customer/block, 9 (i,j) passes.
// M=64 (50 real), activations LDS bf16, weights streamed from L2 ws.
// =====================================================================
__global__ __launch_bounds__(256, 2) void utility(
    const float* __restrict__ X, const float* __restrict__ Wlast,
    const short* __restrict__ pk, const float* __restrict__ preZ,
    const short* __restrict__ XI, float* __restrict__ out)
{
    __shared__ __align__(16) short sA0[64 * 72];    // concat input, stride 72
    __shared__ __align__(16) short sU0[64 * 136];   // stride 136
    __shared__ __align__(16) short sU1[64 * 136];
    __shared__ float sPreZ[3 * WUW];
    __shared__ float sWlast[WUW];
    __shared__ float sPart[200];

    const int tid = threadIdx.x;
    const int w = tid >> 6, lane = tid & 63;
    const int quad = lane >> 4, l15 = lane & 15;
    const int mp = w & 1, nh = w >> 1;     // wave: m-tiles {2mp,2mp+1} x n-tiles {4nh..4nh+3}
    const long b = blockIdx.x;

    if (tid < WUW) sWlast[tid] = Wlast[tid];
    for (int idx = tid; idx < 3 * WUW; idx += 256) sPreZ[idx] = preZ[b * (3 * WUW) + idx];

    float accv = 0.f;
    const float inv_norm = 1.0f / (1.0f + 1e-6f * (float)NPROD);

    for (int i = 0; i < 3; ++i) {
        // ---- build A0 = [X(32) | Xi_i(16) | 0(16)], rows>=50 zero ----
        __syncthreads();
        for (int idx = tid; idx < 64 * 72; idx += 256) sA0[idx] = 0;
        __syncthreads();
        for (int idx = tid; idx < NPROD * 32; idx += 256) {
            int r = idx >> 5, c = idx & 31;
            sA0[r * 72 + c] = f2bf(X[(b * NPROD + r) * 32 + c]);
        }
        for (int idx = tid; idx < NPROD * 16; idx += 256) {
            int r = idx >> 4, c = idx & 15;
            sA0[r * 72 + 32 + c] = XI[((long)i * 409600 + b * NPROD + r) * 16 + c];
        }
        __syncthreads();

        for (int j = 0; j < 3; ++j) {
            float4_ acc[2][4];
            // ---- u0: A0[64x64] @ WU0P[64x128], C init = preZ[j] ----
            #pragma unroll
            for (int mi = 0; mi < 2; ++mi)
                #pragma unroll
                for (int ni = 0; ni < 4; ++ni) {
                    float pz = sPreZ[j * WUW + nh * 64 + ni * 16 + l15];
                    acc[mi][ni] = (float4_)pz;
                }
            #pragma unroll
            for (int ks = 0; ks < 2; ++ks) {
                short8 a[2], bfr[4];
                #pragma unroll
                for (int mi = 0; mi < 2; ++mi) {
                    int mt = mp * 2 + mi;
                    a[mi] = *(const short8*)(sA0 + (mt * 16 + l15) * 72 + ks * 32 + quad * 8);
                }
                #pragma unroll
                for (int ni = 0; ni < 4; ++ni)
                    bfr[ni] = *(const short8*)(pk + PK_WU0 +
                        ((ks * 4 + quad) * 128 + nh * 64 + ni * 16 + l15) * 8);
                #pragma unroll
                for (int mi = 0; mi < 2; ++mi)
                    #pragma unroll
                    for (int ni = 0; ni < 4; ++ni)
                        acc[mi][ni] = MFMA16(a[mi], bfr[ni], acc[mi][ni]);
            }
            #pragma unroll
            for (int mi = 0; mi < 2; ++mi)
                #pragma unroll
                for (int ni = 0; ni < 4; ++ni) {
                    int row0 = (mp * 2 + mi) * 16 + quad * 4;
                    int c = nh * 64 + ni * 16 + l15;
                    #pragma unroll
                    for (int r = 0; r < 4; ++r)
                        sU0[(row0 + r) * 136 + c] = f2bf(elu_f(acc[mi][ni][r]));
                }
            __syncthreads();

            // ---- d1, d2: [64x128] @ [128x128] ----
            for (int l = 0; l < 2; ++l) {
                const short* sIn = l == 0 ? sU0 : sU1;
                short* sOut = l == 0 ? sU1 : sU0;
                const short* B = pk + PK_WU + l * 16384;
                #pragma unroll
                for (int mi = 0; mi < 2; ++mi)
                    #pragma unroll
                    for (int ni = 0; ni < 4; ++ni) acc[mi][ni] = (float4_)0.f;
                #pragma unroll
                for (int ks = 0; ks < 4; ++ks) {
                    short8 a[2], bfr[4];
                    #pragma unroll
                    for (int mi = 0; mi < 2; ++mi) {
                        int mt = mp * 2 + mi;
                        a[mi] = *(const short8*)(sIn + (mt * 16 + l15) * 136 + ks * 32 + quad * 8);
                    }
                    #pragma unroll
                    for (int ni = 0; ni < 4; ++ni)
                        bfr[ni] = *(const short8*)(B +
                            ((ks * 4 + quad) * 128 + nh * 64 + ni * 16 + l15) * 8);
                    #pragma unroll
                    for (int mi = 0; mi < 2; ++mi)
                        #pragma unroll
                        for (int ni = 0; ni < 4; ++ni)
                            acc[mi][ni] = MFMA16(a[mi], bfr[ni], acc[mi][ni]);
                }
                #pragma unroll
                for (int mi = 0; mi < 2; ++mi)
                    #pragma unroll
                    for (int ni = 0; ni < 4; ++ni) {
                        int row0 = (mp * 2 + mi) * 16 + quad * 4;
                        int c = nh * 64 + ni * 16 + l15;
                        #pragma unroll
                        for (int r = 0; r < 4; ++r)
                            sOut[(row0 + r) * 136 + c] = f2bf(elu_f(acc[mi][ni][r]));
                    }
                __syncthreads();
            }

            // ---- score = u @ Wlast, partial dots (4 threads/row) ----
            if (tid < 200) {
                int r = tid >> 2, part = tid & 3;
                float s = 0.f;
                #pragma unroll
                for (int q = 0; q < 4; ++q) {
                    short8 v = *(const short8*)(sU0 + r * 136 + part * 32 + q * 8);
                    #pragma unroll
                    for (int e = 0; e < 8; ++e)
                        s = fmaf(bf2f(v[e]), sWlast[part * 32 + q * 8 + e], s);
                }
                sPart[tid] = s;
            }
            __syncthreads();
            if (tid < 64) {
                float sc = -3.0e38f;
                if (tid < NPROD)
                    sc = sPart[tid * 4] + sPart[tid * 4 + 1] + sPart[tid * 4 + 2] + sPart[tid * 4 + 3];
                float m = sc;
                #pragma unroll
                for (int off = 32; off > 0; off >>= 1) m = fmaxf(m, __shfl_xor(m, off));
                float e = (tid < NPROD) ? expf(sc - m) : 0.f;
                float ssum = e;
                #pragma unroll
                for (int off = 32; off > 0; off >>= 1) ssum += __shfl_xor(ssum, off);
                if (tid < NPROD) accv += (1e-6f + e / ssum) * inv_norm;
            }
            __syncthreads();
        }
    }
    if (tid < NPROD) out[b * NPROD + tid] = accv * (1.0f / 9.0f);
}

// =====================================================================
// Fallback (round-1 fp32 kernel, known-good) if ws is too small
// =====================================================================
template<int IN, int OUT, bool ACT>
__device__ __forceinline__ void dense50(const float* __restrict__ in_lds,
                                        const float* __restrict__ Wg,
                                        float* __restrict__ out_lds)
{
    const int tid = threadIdx.x;
    constexpr int CQ = OUT / 4;
    const float4* __restrict__ W4 = (const float4*)Wg;
    for (int item = tid; item < 25 * CQ; item += 256) {
        const int rp = item / CQ, cq = item % CQ;
        const int r0 = rp, r1 = rp + 25;
        float4 a0 = {0,0,0,0}, a1 = {0,0,0,0};
        for (int k = 0; k < IN; ++k) {
            const float4 wv = W4[k * CQ + cq];
            const float x0 = in_lds[r0 * IN + k], x1 = in_lds[r1 * IN + k];
            a0.x = fmaf(x0, wv.x, a0.x); a0.y = fmaf(x0, wv.y, a0.y);
            a0.z = fmaf(x0, wv.z, a0.z); a0.w = fmaf(x0, wv.w, a0.w);
            a1.x = fmaf(x1, wv.x, a1.x); a1.y = fmaf(x1, wv.y, a1.y);
            a1.z = fmaf(x1, wv.z, a1.z); a1.w = fmaf(x1, wv.w, a1.w);
        }
        if (ACT) {
            a0.x = elu_f(a0.x); a0.y = elu_f(a0.y); a0.z = elu_f(a0.z); a0.w = elu_f(a0.w);
            a1.x = elu_f(a1.x); a1.y = elu_f(a1.y); a1.z = elu_f(a1.z); a1.w = elu_f(a1.w);
        }
        ((float4*)out_lds)[r0 * CQ + cq] = a0;
        ((float4*)out_lds)[r1 * CQ + cq] = a1;
    }
}
template<bool ACT>
__device__ __forceinline__ void dense128fb(const float* __restrict__ in_lds,
                                           const float* __restrict__ Wg,
                                           float* __restrict__ out_lds)
{
    const int tid = threadIdx.x;
    const float4* __restrict__ W4 = (const float4*)Wg;
    for (int item = tid; item < 13 * 32; item += 256) {
        const int rg = item >> 5, cq = item & 31;
        int r[4];
        #pragma unroll
        for (int t = 0; t < 4; ++t) r[t] = min(rg * 4 + t, NPROD - 1);
        float4 a[4];
        #pragma unroll
        for (int t = 0; t < 4; ++t) a[t] = make_float4(0, 0, 0, 0);
        for (int k = 0; k < 128; ++k) {
            const float4 wv = W4[k * 32 + cq];
            #pragma unroll
            for (int t = 0; t < 4; ++t) {
                const float x = in_lds[r[t] * 128 + k];
                a[t].x = fmaf(x, wv.x, a[t].x); a[t].y = fmaf(x, wv.y, a[t].y);
                a[t].z = fmaf(x, wv.z, a[t].z); a[t].w = fmaf(x, wv.w, a[t].w);
            }
        }
        #pragma unroll
        for (int t = 0; t < 4; ++t) {
            const int row = rg * 4 + t;
            if (row < NPROD) {
                float4 o = a[t];
                if (ACT) { o.x = elu_f(o.x); o.y = elu_f(o.y); o.z = elu_f(o.z); o.w = elu_f(o.w); }
                ((float4*)out_lds)[row * 32 + cq] = o;
            }
        }
    }
}
__device__ __forceinline__ void dense_u0fb(const float* __restrict__ sXb,
                                           const float* __restrict__ sXi,
                                           const float* __restrict__ preZ_j,
                                           const float* __restrict__ Wu0,
                                           float* __restrict__ out_lds)
{
    const int tid = threadIdx.x;
    const float4* __restrict__ W4 = (const float4*)Wu0;
    const float4* __restrict__ PZ4 = (const float4*)preZ_j;
    for (int item = tid; item < 13 * 32; item += 256) {
        const int rg = item >> 5, cq = item & 31;
        int r[4];
        #pragma unroll
        for (int t = 0; t < 4; ++t) r[t] = min(rg * 4 + t, NPROD - 1);
        const float4 pz = PZ4[cq];
        float4 a[4];
        #pragma unroll
        for (int t = 0; t < 4; ++t) a[t] = pz;
        for (int k = 0; k < DXF; ++k) {
            const float4 wv = W4[k * 32 + cq];
            #pragma unroll
            for (int t = 0; t < 4; ++t) {
                const float x = sXb[r[t] * DXF + k];
                a[t].x = fmaf(x, wv.x, a[t].x); a[t].y = fmaf(x, wv.y, a[t].y);
                a[t].z = fmaf(x, wv.z, a[t].z); a[t].w = fmaf(x, wv.w, a[t].w);
            }
        }
        for (int k = 0; k < LXD; ++k) {
            const float4 wv = W4[(DXF + k) * 32 + cq];
            #pragma unroll
            for (int t = 0; t < 4; ++t) {
                const float x = sXi[r[t] * LXD + k];
                a[t].x = fmaf(x, wv.x, a[t].x); a[t].y = fmaf(x, wv.y, a[t].y);
                a[t].z = fmaf(x, wv.z, a[t].z); a[t].w = fmaf(x, wv.w, a[t].w);
            }
        }
        #pragma unroll
        for (int t = 0; t < 4; ++t) {
            const int row = rg * 4 + t;
            if (row < NPROD) {
                float4 o = a[t];
                o.x = elu_f(o.x); o.y = elu_f(o.y); o.z = elu_f(o.z); o.w = elu_f(o.w);
                ((float4*)out_lds)[row * 32 + cq] = o;
            }
        }
    }
}
__global__ __launch_bounds__(256, 2) void rum_fused_fb(
    const float* __restrict__ X, const float* __restrict__ Z,
    const float* __restrict__ Wx0, const float* __restrict__ Wx,
    const float* __restrict__ Wlx, const float* __restrict__ Wz0,
    const float* __restrict__ Wz, const float* __restrict__ Wlz,
    const float* __restrict__ Wu0, const float* __restrict__ Wu,
    const float* __restrict__ Wlast, float* __restrict__ out)
{
    __shared__ __align__(16) float sBufA[NPROD * WUW];
    __shared__ __align__(16) float sBufB[NPROD * WUW];
    __shared__ __align__(16) float sXb[NPROD * DXF];
    __shared__ __align__(16) float sXi[NPROD * LXD];
    __shared__ __align__(16) float sPreZ[3 * WUW];
    const int b = blockIdx.x, tid = threadIdx.x;
    float* zsm = sBufA; float* zh0 = sBufA + 64; float* zh1 = sBufA + 256; float* zjd = sBufA + 448;
    {
        const float* Xg = X + (size_t)b * (NPROD * DXF);
        for (int idx = tid; idx < NPROD * DXF; idx += 256) sXb[idx] = Xg[idx];
        const float* Zg = Z + (size_t)b * DZF;
        if (tid < DZF) zsm[tid] = Zg[tid];
    }
    __syncthreads();
    const int zj = tid >> 6, zc = tid & 63;
    if (zj < 3) { const float* wv = Wz0 + zj * (DZF * 64); float s = 0;
        for (int k = 0; k < DZF; ++k) s = fmaf(zsm[k], wv[k * 64 + zc], s);
        zh0[zj * 64 + zc] = elu_f(s); }
    __syncthreads();
    if (zj < 3) { const float* wv = Wz + (zj * 2 + 0) * 4096; float s = 0;
        for (int k = 0; k < 64; ++k) s = fmaf(zh0[zj * 64 + k], wv[k * 64 + zc], s);
        zh1[zj * 64 + zc] = elu_f(s); }
    __syncthreads();
    if (zj < 3) { const float* wv = Wz + (zj * 2 + 1) * 4096; float s = 0;
        for (int k = 0; k < 64; ++k) s = fmaf(zh1[zj * 64 + k], wv[k * 64 + zc], s);
        zh0[zj * 64 + zc] = elu_f(s); }
    __syncthreads();
    if (tid < 48) { const int j = tid >> 4, c = tid & 15;
        const float* wv = Wlz + j * (64 * LZD); float s = 0;
        for (int k = 0; k < 64; ++k) s = fmaf(zh0[j * 64 + k], wv[k * LZD + c], s);
        zjd[j * LZD + c] = s; }
    __syncthreads();
    for (int idx = tid; idx < 3 * WUW; idx += 256) {
        const int j = idx >> 7, c = idx & 127; float s = 0;
        for (int k = 0; k < LZD; ++k) s = fmaf(zjd[j * LZD + k], Wu0[(DXF + LXD + k) * WUW + c], s);
        for (int k = 0; k < DZF; ++k) s = fmaf(zsm[k], Wu0[(DXF + LXD + LZD + k) * WUW + c], s);
        sPreZ[idx] = s;
    }
    __syncthreads();
    float accv = 0.f;
    const float inv_norm = 1.0f / (1.0f + 1e-6f * (float)NPROD);
    for (int i = 0; i < 3; ++i) {
        dense50<DXF, 64, true>(sXb, Wx0 + i * (DXF * 64), sBufA); __syncthreads();
        dense50<64, 64, true>(sBufA, Wx + (i * 2 + 0) * 4096, sBufB); __syncthreads();
        dense50<64, 64, true>(sBufB, Wx + (i * 2 + 1) * 4096, sBufA); __syncthreads();
        dense50<64, LXD, false>(sBufA, Wlx + 2 * (64 * LXD), sXi); __syncthreads();
        for (int j = 0; j < 3; ++j) {
            dense_u0fb(sXb, sXi, sPreZ + j * WUW, Wu0, sBufA); __syncthreads();
            dense128fb<true>(sBufA, Wu, sBufB); __syncthreads();
            dense128fb<true>(sBufB, Wu + 16384, sBufA); __syncthreads();
            if (tid < 64) {
                float sc = -3.0e38f;
                if (tid < NPROD) { float s = 0;
                    for (int k = 0; k < WUW; ++k) s = fmaf(sBufA[tid * WUW + k], Wlast[k], s);
                    sc = s; }
                float m = sc;
                #pragma unroll
                for (int off = 32; off > 0; off >>= 1) m = fmaxf(m, __shfl_xor(m, off));
                float e = (tid < NPROD) ? expf(sc - m) : 0.f;
                float ssum = e;
                #pragma unroll
                for (int off = 32; off > 0; off >>= 1) ssum += __shfl_xor(ssum, off);
                if (tid < NPROD) accv += (1e-6f + e / ssum) * inv_norm;
            }
            __syncthreads();
        }
    }
    if (tid < NPROD) out[(size_t)b * NPROD + tid] = accv * (1.0f / 9.0f);
}

// =====================================================================
extern "C" void kernel_launch(void* const* d_in, const int* in_sizes, int n_in,
                              void* d_out, int out_size, void* d_ws, size_t ws_size,
                              hipStream_t stream) {
    const float* X     = (const float*)d_in[0];
    const float* Z     = (const float*)d_in[1];
    const float* Wx0   = (const float*)d_in[2];
    const float* Wx    = (const float*)d_in[3];
    const float* Wlx   = (const float*)d_in[4];
    const float* Wz0   = (const float*)d_in[5];
    const float* Wz    = (const float*)d_in[6];
    const float* Wlz   = (const float*)d_in[7];
    const float* Wu0   = (const float*)d_in[8];
    const float* Wu    = (const float*)d_in[9];
    const float* Wlast = (const float*)d_in[10];
    float* out = (float*)d_out;

    if (ws_size < WS_NEEDED) {
        rum_fused_fb<<<dim3(8192), dim3(256), 0, stream>>>(
            X, Z, Wx0, Wx, Wlx, Wz0, Wz, Wlz, Wu0, Wu, Wlast, out);
        return;
    }

    char* wsB = (char*)d_ws;
    short* pk    = (short*)wsB;
    float* preZ  = (float*)(wsB + PREZ_OFF_B);
    short* XI    = (short*)(wsB + XI_OFF_B);

    pack_weights<<<dim3((PK_TOTAL + 255) / 256), dim3(256), 0, stream>>>(
        Wx0, Wx, Wlx, Wu0, Wu, pk);
    z_prez<<<dim3(8192 / 4), dim3(256), 0, stream>>>(Z, Wz0, Wz, Wlz, Wu0, preZ);
    x_branch<<<dim3(409600 / 128), dim3(256), 0, stream>>>(X, pk, XI);
    utility<<<dim3(8192), dim3(256), 0, stream>>>(X, Wlast, pk, preZ, XI, out);
}

// Round 3
// 1288.709 us; speedup vs baseline: 26.9411x; 1.5526x over previous
//
#include <hip/hip_runtime.h>
#include <math.h>

#define NPROD 50
#define DXF 32
#define DZF 20
#define WUW 128
#define LXD 16
#define LZD 16

typedef __attribute__((ext_vector_type(8))) short short8;
typedef __attribute__((ext_vector_type(4))) float float4_;

__device__ __forceinline__ float elu_fast(float x) {
    float e = __builtin_amdgcn_exp2f(x * 1.44269504089f) - 1.0f;
    return x > 0.0f ? x : e;
}
__device__ __forceinline__ short f2bf(float x) {
    unsigned u = __builtin_bit_cast(unsigned, x);
    u += 0x7fffu + ((u >> 16) & 1u);
    return (short)(u >> 16);
}
__device__ __forceinline__ unsigned pkbf(float a, float b) {
#if __has_builtin(__builtin_amdgcn_cvt_pk_bf16_f32)
    auto v = __builtin_amdgcn_cvt_pk_bf16_f32(a, b);
    return __builtin_bit_cast(unsigned, v);
#else
    return (unsigned)(unsigned short)f2bf(a) | ((unsigned)(unsigned short)f2bf(b) << 16);
#endif
}
#define MFMA16(a, b, c) __builtin_amdgcn_mfma_f32_16x16x32_bf16((a), (b), (c), 0, 0, 0)

// ---------------- ws layout ----------------
// All weights packed bf16 in A-operand layout: pk[n*K + k] = W[k][n]
#define PK_WX0   0        // 3 x [64][32]
#define PK_WX    6144     // 6 x [64][64]
#define PK_WLX2  30720    // [16][64]   (leaked-k: Wlx[2] only)
#define PK_WU0   31744    // [128][64]  (K 48 real, 48..63 zero)
#define PK_WU    39936    // 2 x [128][128]
#define PK_WLAST 72704    // [16][128]  (row 0 = Wlast, rest zero)
#define PK_TOTAL 74752
#define PREZ_OFF_B  151552
#define WS_NEEDED   (PREZ_OFF_B + (size_t)8192*3*128*4)

// =====================================================================
// Kernel 1: pack fp32 weights -> bf16 A-operand layout [n][k]
// =====================================================================
__global__ void pack_weights(const float* __restrict__ Wx0, const float* __restrict__ Wx,
                             const float* __restrict__ Wlx, const float* __restrict__ Wu0,
                             const float* __restrict__ Wu, const float* __restrict__ Wlast,
                             short* __restrict__ pk)
{
    int idx = blockIdx.x * 256 + threadIdx.x;
    if (idx >= PK_TOTAL) return;
    float v;
    if (idx < PK_WX) {
        int m = idx / 2048, r = idx % 2048, n = r / 32, k = r % 32;
        v = Wx0[m * 2048 + k * 64 + n];
    } else if (idx < PK_WLX2) {
        int t = idx - PK_WX; int m = t / 4096, r = t % 4096, n = r / 64, k = r % 64;
        v = Wx[m * 4096 + k * 64 + n];
    } else if (idx < PK_WU0) {
        int r = idx - PK_WLX2; int n = r / 64, k = r % 64;
        v = Wlx[2 * 1024 + k * 16 + n];
    } else if (idx < PK_WU) {
        int r = idx - PK_WU0; int n = r / 64, k = r % 64;
        v = (k < 48) ? Wu0[k * 128 + n] : 0.0f;
    } else if (idx < PK_WLAST) {
        int t = idx - PK_WU; int m = t / 16384, r = t % 16384, n = r / 128, k = r % 128;
        v = Wu[m * 16384 + k * 128 + n];
    } else {
        int r = idx - PK_WLAST; int n = r / 128, k = r % 128;
        v = (n == 0) ? Wlast[k] : 0.0f;
    }
    pk[idx] = f2bf(v);
}

// =====================================================================
// Kernel 2: Z-branch + preZ[b][j][:] (fp32, unchanged from R2 - passed)
// =====================================================================
__global__ __launch_bounds__(256, 4) void z_prez(
    const float* __restrict__ Z, const float* __restrict__ Wz0,
    const float* __restrict__ Wz, const float* __restrict__ Wlz,
    const float* __restrict__ Wu0, float* __restrict__ preZ)
{
    __shared__ float sZ[4][DZF], sH0[4][64], sH1[4][64], sZj[4][LZD];
    const int tid = threadIdx.x;
    const int cu = tid >> 6, col = tid & 63;
    const int b0 = blockIdx.x * 4;
    if (tid < 80) sZ[tid / DZF][tid % DZF] = Z[(size_t)(b0 + tid / DZF) * DZF + tid % DZF];
    __syncthreads();
    for (int j = 0; j < 3; ++j) {
        { const float* w = Wz0 + j * (DZF * 64);
          float s = 0.f;
          for (int k = 0; k < DZF; ++k) s = fmaf(sZ[cu][k], w[k * 64 + col], s);
          sH0[cu][col] = elu_fast(s); }
        __syncthreads();
        { const float* w = Wz + (j * 2 + 0) * 4096;
          float s = 0.f;
          for (int k = 0; k < 64; ++k) s = fmaf(sH0[cu][k], w[k * 64 + col], s);
          sH1[cu][col] = elu_fast(s); }
        __syncthreads();
        { const float* w = Wz + (j * 2 + 1) * 4096;
          float s = 0.f;
          for (int k = 0; k < 64; ++k) s = fmaf(sH1[cu][k], w[k * 64 + col], s);
          sH0[cu][col] = elu_fast(s); }
        __syncthreads();
        if (col < LZD) {
            const float* w = Wlz + j * (64 * LZD);
            float s = 0.f;
            for (int k = 0; k < 64; ++k) s = fmaf(sH0[cu][k], w[k * LZD + col], s);
            sZj[cu][col] = s;
        }
        __syncthreads();
        for (int half = 0; half < 2; ++half) {
            const int c = col + half * 64;
            float s = 0.f;
            for (int k = 0; k < LZD; ++k) s = fmaf(sZj[cu][k], Wu0[(48 + k) * WUW + c], s);
            for (int k = 0; k < DZF; ++k) s = fmaf(sZ[cu][k], Wu0[(64 + k) * WUW + c], s);
            preZ[((size_t)(b0 + cu) * 3 + j) * WUW + c] = s;
        }
        __syncthreads();
    }
}

// =====================================================================
// Kernel 3: fused x-branch + utility. One customer per block.
// Weights = A operand (from L2-resident pk), activations = B operand
// (LDS, [m][k] row-major -> contiguous b128 reads, b64 packed writes).
// D lane layout: col=m=lane&15, rows=4 consecutive out-channels.
// =====================================================================
template<bool ACT>
__device__ __forceinline__ void store_tile(short* buf, int stride, int pt, int n0,
                                           int l15, int quad, float4_ a)
{
    float e0, e1, e2, e3;
    if (ACT) { e0 = elu_fast(a[0]); e1 = elu_fast(a[1]); e2 = elu_fast(a[2]); e3 = elu_fast(a[3]); }
    else { e0 = a[0]; e1 = a[1]; e2 = a[2]; e3 = a[3]; }
    uint2 p; p.x = pkbf(e0, e1); p.y = pkbf(e2, e3);
    *(uint2*)(buf + (pt * 16 + l15) * stride + n0 + quad * 4) = p;
}

__global__ __launch_bounds__(256, 3) void rum_main(
    const float* __restrict__ X, const short* __restrict__ pk,
    const float* __restrict__ preZ, float* __restrict__ out)
{
    __shared__ __align__(16) short sA0[64 * 72];    // [m][k]: 0..31 X, 32..47 Xi, 48..63 zero
    __shared__ __align__(16) short sU0[64 * 136];   // [m][n]
    __shared__ __align__(16) short sU1[64 * 136];
    __shared__ __align__(16) float sPreZ[3 * 128];
    __shared__ float sScore[64];

    const int tid = threadIdx.x;
    const int w = tid >> 6, lane = tid & 63;
    const int quad = lane >> 4, l15 = lane & 15;
    const long b = blockIdx.x;

    // zero dead k-columns 48..63 (their pk rows are zero, but stale LDS could be NaN)
    { int r = tid >> 2, c = 48 + (tid & 3) * 4;
      *(uint2*)(sA0 + r * 72 + c) = make_uint2(0u, 0u); }

    // stage X (50x32 fp32 -> bf16), vectorized
    for (int it = tid; it < 400; it += 256) {
        int r = it >> 3, c4 = it & 7;
        float4_ xv = *(const float4_*)(X + (b * 50 + r) * 32 + c4 * 4);
        uint2 p; p.x = pkbf(xv[0], xv[1]); p.y = pkbf(xv[2], xv[3]);
        *(uint2*)(sA0 + r * 72 + c4 * 4) = p;
    }
    if (tid < 96)
        *(float4_*)(sPreZ + tid * 4) = *(const float4_*)(preZ + b * 384 + tid * 4);
    __syncthreads();

    float accv = 0.f;
    const float inv_norm = 1.0f / (1.0f + 1e-6f * (float)NPROD);

    for (int i = 0; i < 3; ++i) {
        // ---- x l0: Wx0_i[64ch][32k] @ X^T -> sU0 cols 0..63 ----
        {
            const short* A = pk + PK_WX0 + i * 2048;
            short8 af = *(const short8*)(A + (w * 16 + l15) * 32 + quad * 8);
            #pragma unroll
            for (int pt = 0; pt < 4; ++pt) {
                short8 bf = *(const short8*)(sA0 + (pt * 16 + l15) * 72 + quad * 8);
                float4_ acc = MFMA16(af, bf, (float4_)0.f);
                store_tile<true>(sU0, 136, pt, w * 16, l15, quad, acc);
            }
        }
        __syncthreads();

        // ---- x l1, l2: Wx[2i+l][64][64] ----
        for (int l = 0; l < 2; ++l) {
            const short* A = pk + PK_WX + (i * 2 + l) * 4096;
            const short* sIn = l ? sU1 : sU0;
            short* sOut = l ? sU0 : sU1;
            short8 af0 = *(const short8*)(A + (w * 16 + l15) * 64 + quad * 8);
            short8 af1 = *(const short8*)(A + (w * 16 + l15) * 64 + 32 + quad * 8);
            #pragma unroll
            for (int pt = 0; pt < 4; ++pt) {
                short8 b0 = *(const short8*)(sIn + (pt * 16 + l15) * 136 + quad * 8);
                short8 b1 = *(const short8*)(sIn + (pt * 16 + l15) * 136 + 32 + quad * 8);
                float4_ acc = MFMA16(af0, b0, (float4_)0.f);
                acc = MFMA16(af1, b1, acc);
                store_tile<true>(sOut, 136, pt, w * 16, l15, quad, acc);
            }
            __syncthreads();
        }

        // ---- x ll: Wlx[2][16ch][64k], linear; write Xi into sA0 cols 32..47 ----
        {
            const short* A = pk + PK_WLX2;
            short8 af0 = *(const short8*)(A + l15 * 64 + quad * 8);
            short8 af1 = *(const short8*)(A + l15 * 64 + 32 + quad * 8);
            short8 b0 = *(const short8*)(sU0 + (w * 16 + l15) * 136 + quad * 8);
            short8 b1 = *(const short8*)(sU0 + (w * 16 + l15) * 136 + 32 + quad * 8);
            float4_ acc = MFMA16(af0, b0, (float4_)0.f);
            acc = MFMA16(af1, b1, acc);
            store_tile<false>(sA0, 72, w, 32, l15, quad, acc);
        }
        __syncthreads();

        for (int j = 0; j < 3; ++j) {
            // ---- u0: Wu0p[128][64] @ A0^T, C init = preZ[j] ----
            {
                const short* A = pk + PK_WU0;
                short8 b0s[4], b1s[4];
                #pragma unroll
                for (int pt = 0; pt < 4; ++pt) {
                    b0s[pt] = *(const short8*)(sA0 + (pt * 16 + l15) * 72 + quad * 8);
                    b1s[pt] = *(const short8*)(sA0 + (pt * 16 + l15) * 72 + 32 + quad * 8);
                }
                #pragma unroll
                for (int wi = 0; wi < 2; ++wi) {
                    const int wt = w * 2 + wi;
                    float4_ pz = *(const float4_*)(sPreZ + j * 128 + wt * 16 + quad * 4);
                    short8 af0 = *(const short8*)(A + (wt * 16 + l15) * 64 + quad * 8);
                    short8 af1 = *(const short8*)(A + (wt * 16 + l15) * 64 + 32 + quad * 8);
                    #pragma unroll
                    for (int pt = 0; pt < 4; ++pt) {
                        float4_ t = MFMA16(af0, b0s[pt], pz);
                        t = MFMA16(af1, b1s[pt], t);
                        store_tile<true>(sU0, 136, pt, wt * 16, l15, quad, t);
                    }
                }
            }
            __syncthreads();

            // ---- d1, d2: Wu[l][128][128] ----
            for (int l = 0; l < 2; ++l) {
                const short* A = pk + PK_WU + l * 16384;
                const short* sIn = l ? sU1 : sU0;
                short* sOut = l ? sU0 : sU1;
                float4_ acc2[2][4];
                #pragma unroll
                for (int wi = 0; wi < 2; ++wi)
                    #pragma unroll
                    for (int pt = 0; pt < 4; ++pt) acc2[wi][pt] = (float4_)0.f;
                #pragma unroll
                for (int ks = 0; ks < 4; ++ks) {
                    short8 bf[4];
                    #pragma unroll
                    for (int pt = 0; pt < 4; ++pt)
                        bf[pt] = *(const short8*)(sIn + (pt * 16 + l15) * 136 + ks * 32 + quad * 8);
                    #pragma unroll
                    for (int wi = 0; wi < 2; ++wi) {
                        short8 af = *(const short8*)(A + ((w * 2 + wi) * 16 + l15) * 128 + ks * 32 + quad * 8);
                        #pragma unroll
                        for (int pt = 0; pt < 4; ++pt)
                            acc2[wi][pt] = MFMA16(af, bf[pt], acc2[wi][pt]);
                    }
                }
                #pragma unroll
                for (int wi = 0; wi < 2; ++wi)
                    #pragma unroll
                    for (int pt = 0; pt < 4; ++pt)
                        store_tile<true>(sOut, 136, pt, (w * 2 + wi) * 16, l15, quad, acc2[wi][pt]);
                __syncthreads();
            }

            // ---- score: pkWlast[16][128] @ u2^T; row 0 = score ----
            {
                const short* A = pk + PK_WLAST;
                float4_ acc1 = (float4_)0.f;
                #pragma unroll
                for (int ks = 0; ks < 4; ++ks) {
                    short8 af = *(const short8*)(A + l15 * 128 + ks * 32 + quad * 8);
                    short8 bf = *(const short8*)(sU0 + (w * 16 + l15) * 136 + ks * 32 + quad * 8);
                    acc1 = MFMA16(af, bf, acc1);
                }
                if (quad == 0) sScore[w * 16 + l15] = acc1[0];
            }
            __syncthreads();

            // ---- softmax (wave 0) ----
            if (tid < 64) {
                float sc = (tid < NPROD) ? sScore[tid] : -3.0e38f;
                float m = sc;
                #pragma unroll
                for (int off = 32; off > 0; off >>= 1) m = fmaxf(m, __shfl_xor(m, off));
                float e = (tid < NPROD) ? __builtin_amdgcn_exp2f((sc - m) * 1.44269504089f) : 0.f;
                float ssum = e;
                #pragma unroll
                for (int off = 32; off > 0; off >>= 1) ssum += __shfl_xor(ssum, off);
                if (tid < NPROD) accv += (1e-6f + e / ssum) * inv_norm;
            }
            __syncthreads();
        }
    }
    if (tid < NPROD) out[b * 50 + tid] = accv * (1.0f / 9.0f);
}

// =====================================================================
// Fallback (round-1 fp32 kernel, known-good) if ws too small
// =====================================================================
__device__ __forceinline__ float elu_f(float x) { return x > 0.0f ? x : expm1f(x); }
template<int IN, int OUT, bool ACT>
__device__ __forceinline__ void dense50(const float* __restrict__ in_lds,
                                        const float* __restrict__ Wg,
                                        float* __restrict__ out_lds)
{
    const int tid = threadIdx.x;
    constexpr int CQ = OUT / 4;
    const float4* __restrict__ W4 = (const float4*)Wg;
    for (int item = tid; item < 25 * CQ; item += 256) {
        const int rp = item / CQ, cq = item % CQ;
        const int r0 = rp, r1 = rp + 25;
        float4 a0 = {0,0,0,0}, a1 = {0,0,0,0};
        for (int k = 0; k < IN; ++k) {
            const float4 wv = W4[k * CQ + cq];
            const float x0 = in_lds[r0 * IN + k], x1 = in_lds[r1 * IN + k];
            a0.x = fmaf(x0, wv.x, a0.x); a0.y = fmaf(x0, wv.y, a0.y);
            a0.z = fmaf(x0, wv.z, a0.z); a0.w = fmaf(x0, wv.w, a0.w);
            a1.x = fmaf(x1, wv.x, a1.x); a1.y = fmaf(x1, wv.y, a1.y);
            a1.z = fmaf(x1, wv.z, a1.z); a1.w = fmaf(x1, wv.w, a1.w);
        }
        if (ACT) {
            a0.x = elu_f(a0.x); a0.y = elu_f(a0.y); a0.z = elu_f(a0.z); a0.w = elu_f(a0.w);
            a1.x = elu_f(a1.x); a1.y = elu_f(a1.y); a1.z = elu_f(a1.z); a1.w = elu_f(a1.w);
        }
        ((float4*)out_lds)[r0 * CQ + cq] = a0;
        ((float4*)out_lds)[r1 * CQ + cq] = a1;
    }
}
template<bool ACT>
__device__ __forceinline__ void dense128fb(const float* __restrict__ in_lds,
                                           const float* __restrict__ Wg,
                                           float* __restrict__ out_lds)
{
    const int tid = threadIdx.x;
    const float4* __restrict__ W4 = (const float4*)Wg;
    for (int item = tid; item < 13 * 32; item += 256) {
        const int rg = item >> 5, cq = item & 31;
        int r[4];
        #pragma unroll
        for (int t = 0; t < 4; ++t) r[t] = min(rg * 4 + t, NPROD - 1);
        float4 a[4];
        #pragma unroll
        for (int t = 0; t < 4; ++t) a[t] = make_float4(0, 0, 0, 0);
        for (int k = 0; k < 128; ++k) {
            const float4 wv = W4[k * 32 + cq];
            #pragma unroll
            for (int t = 0; t < 4; ++t) {
                const float x = in_lds[r[t] * 128 + k];
                a[t].x = fmaf(x, wv.x, a[t].x); a[t].y = fmaf(x, wv.y, a[t].y);
                a[t].z = fmaf(x, wv.z, a[t].z); a[t].w = fmaf(x, wv.w, a[t].w);
            }
        }
        #pragma unroll
        for (int t = 0; t < 4; ++t) {
            const int row = rg * 4 + t;
            if (row < NPROD) {
                float4 o = a[t];
                if (ACT) { o.x = elu_f(o.x); o.y = elu_f(o.y); o.z = elu_f(o.z); o.w = elu_f(o.w); }
                ((float4*)out_lds)[row * 32 + cq] = o;
            }
        }
    }
}
__device__ __forceinline__ void dense_u0fb(const float* __restrict__ sXb,
                                           const float* __restrict__ sXi,
                                           const float* __restrict__ preZ_j,
                                           const float* __restrict__ Wu0,
                                           float* __restrict__ out_lds)
{
    const int tid = threadIdx.x;
    const float4* __restrict__ W4 = (const float4*)Wu0;
    const float4* __restrict__ PZ4 = (const float4*)preZ_j;
    for (int item = tid; item < 13 * 32; item += 256) {
        const int rg = item >> 5, cq = item & 31;
        int r[4];
        #pragma unroll
        for (int t = 0; t < 4; ++t) r[t] = min(rg * 4 + t, NPROD - 1);
        const float4 pz = PZ4[cq];
        float4 a[4];
        #pragma unroll
        for (int t = 0; t < 4; ++t) a[t] = pz;
        for (int k = 0; k < DXF; ++k) {
            const float4 wv = W4[k * 32 + cq];
            #pragma unroll
            for (int t = 0; t < 4; ++t) {
                const float x = sXb[r[t] * DXF + k];
                a[t].x = fmaf(x, wv.x, a[t].x); a[t].y = fmaf(x, wv.y, a[t].y);
                a[t].z = fmaf(x, wv.z, a[t].z); a[t].w = fmaf(x, wv.w, a[t].w);
            }
        }
        for (int k = 0; k < LXD; ++k) {
            const float4 wv = W4[(DXF + k) * 32 + cq];
            #pragma unroll
            for (int t = 0; t < 4; ++t) {
                const float x = sXi[r[t] * LXD + k];
                a[t].x = fmaf(x, wv.x, a[t].x); a[t].y = fmaf(x, wv.y, a[t].y);
                a[t].z = fmaf(x, wv.z, a[t].z); a[t].w = fmaf(x, wv.w, a[t].w);
            }
        }
        #pragma unroll
        for (int t = 0; t < 4; ++t) {
            const int row = rg * 4 + t;
            if (row < NPROD) {
                float4 o = a[t];
                o.x = elu_f(o.x); o.y = elu_f(o.y); o.z = elu_f(o.z); o.w = elu_f(o.w);
                ((float4*)out_lds)[row * 32 + cq] = o;
            }
        }
    }
}
__global__ __launch_bounds__(256, 2) void rum_fused_fb(
    const float* __restrict__ X, const float* __restrict__ Z,
    const float* __restrict__ Wx0, const float* __restrict__ Wx,
    const float* __restrict__ Wlx, const float* __restrict__ Wz0,
    const float* __restrict__ Wz, const float* __restrict__ Wlz,
    const float* __restrict__ Wu0, const float* __restrict__ Wu,
    const float* __restrict__ Wlast, float* __restrict__ out)
{
    __shared__ __align__(16) float sBufA[NPROD * WUW];
    __shared__ __align__(16) float sBufB[NPROD * WUW];
    __shared__ __align__(16) float sXb[NPROD * DXF];
    __shared__ __align__(16) float sXi[NPROD * LXD];
    __shared__ __align__(16) float sPreZ[3 * WUW];
    const int b = blockIdx.x, tid = threadIdx.x;
    float* zsm = sBufA; float* zh0 = sBufA + 64; float* zh1 = sBufA + 256; float* zjd = sBufA + 448;
    {
        const float* Xg = X + (size_t)b * (NPROD * DXF);
        for (int idx = tid; idx < NPROD * DXF; idx += 256) sXb[idx] = Xg[idx];
        const float* Zg = Z + (size_t)b * DZF;
        if (tid < DZF) zsm[tid] = Zg[tid];
    }
    __syncthreads();
    const int zj = tid >> 6, zc = tid & 63;
    if (zj < 3) { const float* wv = Wz0 + zj * (DZF * 64); float s = 0;
        for (int k = 0; k < DZF; ++k) s = fmaf(zsm[k], wv[k * 64 + zc], s);
        zh0[zj * 64 + zc] = elu_f(s); }
    __syncthreads();
    if (zj < 3) { const float* wv = Wz + (zj * 2 + 0) * 4096; float s = 0;
        for (int k = 0; k < 64; ++k) s = fmaf(zh0[zj * 64 + k], wv[k * 64 + zc], s);
        zh1[zj * 64 + zc] = elu_f(s); }
    __syncthreads();
    if (zj < 3) { const float* wv = Wz + (zj * 2 + 1) * 4096; float s = 0;
        for (int k = 0; k < 64; ++k) s = fmaf(zh1[zj * 64 + k], wv[k * 64 + zc], s);
        zh0[zj * 64 + zc] = elu_f(s); }
    __syncthreads();
    if (tid < 48) { const int j = tid >> 4, c = tid & 15;
        const float* wv = Wlz + j * (64 * LZD); float s = 0;
        for (int k = 0; k < 64; ++k) s = fmaf(zh0[j * 64 + k], wv[k * LZD + c], s);
        zjd[j * LZD + c] = s; }
    __syncthreads();
    for (int idx = tid; idx < 3 * WUW; idx += 256) {
        const int j = idx >> 7, c = idx & 127; float s = 0;
        for (int k = 0; k < LZD; ++k) s = fmaf(zjd[j * LZD + k], Wu0[(DXF + LXD + k) * WUW + c], s);
        for (int k = 0; k < DZF; ++k) s = fmaf(zsm[k], Wu0[(DXF + LXD + LZD + k) * WUW + c], s);
        sPreZ[idx] = s;
    }
    __syncthreads();
    float accv = 0.f;
    const float inv_norm = 1.0f / (1.0f + 1e-6f * (float)NPROD);
    for (int i = 0; i < 3; ++i) {
        dense50<DXF, 64, true>(sXb, Wx0 + i * (DXF * 64), sBufA); __syncthreads();
        dense50<64, 64, true>(sBufA, Wx + (i * 2 + 0) * 4096, sBufB); __syncthreads();
        dense50<64, 64, true>(sBufB, Wx + (i * 2 + 1) * 4096, sBufA); __syncthreads();
        dense50<64, LXD, false>(sBufA, Wlx + 2 * (64 * LXD), sXi); __syncthreads();
        for (int j = 0; j < 3; ++j) {
            dense_u0fb(sXb, sXi, sPreZ + j * WUW, Wu0, sBufA); __syncthreads();
            dense128fb<true>(sBufA, Wu, sBufB); __syncthreads();
            dense128fb<true>(sBufB, Wu + 16384, sBufA); __syncthreads();
            if (tid < 64) {
                float sc = -3.0e38f;
                if (tid < NPROD) { float s = 0;
                    for (int k = 0; k < WUW; ++k) s = fmaf(sBufA[tid * WUW + k], Wlast[k], s);
                    sc = s; }
                float m = sc;
                #pragma unroll
                for (int off = 32; off > 0; off >>= 1) m = fmaxf(m, __shfl_xor(m, off));
                float e = (tid < NPROD) ? expf(sc - m) : 0.f;
                float ssum = e;
                #pragma unroll
                for (int off = 32; off > 0; off >>= 1) ssum += __shfl_xor(ssum, off);
                if (tid < NPROD) accv += (1e-6f + e / ssum) * inv_norm;
            }
            __syncthreads();
        }
    }
    if (tid < NPROD) out[(size_t)b * NPROD + tid] = accv * (1.0f / 9.0f);
}

// =====================================================================
extern "C" void kernel_launch(void* const* d_in, const int* in_sizes, int n_in,
                              void* d_out, int out_size, void* d_ws, size_t ws_size,
                              hipStream_t stream) {
    const float* X     = (const float*)d_in[0];
    const float* Z     = (const float*)d_in[1];
    const float* Wx0   = (const float*)d_in[2];
    const float* Wx    = (const float*)d_in[3];
    const float* Wlx   = (const float*)d_in[4];
    const float* Wz0   = (const float*)d_in[5];
    const float* Wz    = (const float*)d_in[6];
    const float* Wlz   = (const float*)d_in[7];
    const float* Wu0   = (const float*)d_in[8];
    const float* Wu    = (const float*)d_in[9];
    const float* Wlast = (const float*)d_in[10];
    float* out = (float*)d_out;

    if (ws_size < WS_NEEDED) {
        rum_fused_fb<<<dim3(8192), dim3(256), 0, stream>>>(
            X, Z, Wx0, Wx, Wlx, Wz0, Wz, Wlz, Wu0, Wu, Wlast, out);
        return;
    }

    char* wsB = (char*)d_ws;
    short* pk   = (short*)wsB;
    float* preZ = (float*)(wsB + PREZ_OFF_B);

    pack_weights<<<dim3((PK_TOTAL + 255) / 256), dim3(256), 0, stream>>>(
        Wx0, Wx, Wlx, Wu0, Wu, Wlast, pk);
    z_prez<<<dim3(8192 / 4), dim3(256), 0, stream>>>(Z, Wz0, Wz, Wlz, Wu0, preZ);
    rum_main<<<dim3(8192), dim3(256), 0, stream>>>(X, pk, preZ, out);
}

// Round 4
// 1263.681 us; speedup vs baseline: 27.4747x; 1.0198x over previous
//
#include <hip/hip_runtime.h>
#include <math.h>

#define NPROD 50
#define DXF 32
#define DZF 20
#define WUW 128
#define LXD 16
#define LZD 16

typedef __attribute__((ext_vector_type(8))) short short8;
typedef __attribute__((ext_vector_type(4))) float float4_;

__device__ __forceinline__ short f2bf(float x) {
    unsigned u = __builtin_bit_cast(unsigned, x);
    u += 0x7fffu + ((u >> 16) & 1u);
    return (short)(u >> 16);
}
__device__ __forceinline__ unsigned pkbf(float a, float b) {
#if __has_builtin(__builtin_amdgcn_cvt_pk_bf16_f32)
    auto v = __builtin_amdgcn_cvt_pk_bf16_f32(a, b);
    return __builtin_bit_cast(unsigned, v);
#else
    return (unsigned)(unsigned short)f2bf(a) | ((unsigned)(unsigned short)f2bf(b) << 16);
#endif
}
// elu(x) = med3(x, exp2(x*log2e)-1, 0): x>0 -> x (since e^x-1>=x>0), x<0 -> e^x-1 in (x,0)
__device__ __forceinline__ float elu_med3(float x) {
    float e = __builtin_amdgcn_exp2f(x * 1.44269504089f) - 1.0f;
#if __has_builtin(__builtin_amdgcn_fmed3f)
    return __builtin_amdgcn_fmed3f(x, e, 0.0f);
#else
    return x > 0.0f ? x : e;
#endif
}
__device__ __forceinline__ float elu_fast(float x) {
    float e = __builtin_amdgcn_exp2f(x * 1.44269504089f) - 1.0f;
    return x > 0.0f ? x : e;
}
#define MFMA16(a, b, c) __builtin_amdgcn_mfma_f32_16x16x32_bf16((a), (b), (c), 0, 0, 0)

// ---------------- ws layout ----------------
// All weights packed bf16, A-operand layout: pk[n*K + k] = W[k][n]
#define PK_WX0   0        // 3 x [64][32]
#define PK_WX    6144     // 6 x [64][64]
#define PK_WLX2  30720    // [16][64]   (leaked-k bug: Wlx[2] only)
#define PK_WU0   31744    // [128][64]  (k 0..31 X, 32..47 Xi, 48..63 zero)
#define PK_WU    39936    // 2 x [128][128]
#define PK_WLAST 72704    // [16][128]  (row 0 = Wlast, rest zero)
#define PK_TOTAL 74752
#define NB_PACK  292      // 74752/256 exactly
#define NB_Z     2048     // 8192/4
#define PREZ_OFF_B  151552
#define WS_NEEDED   (PREZ_OFF_B + (size_t)8192*3*128*4)

// swizzled LDS addressing: 16B chunks XOR'd by row to spread banks (<=2-way all phases)
__device__ __forceinline__ short* su_ptr(short* buf, int row, int chunk) {
    return buf + (row << 7) + ((chunk ^ (row & 15)) << 3);   // row stride 128 shorts
}
__device__ __forceinline__ const short* su_ptr(const short* buf, int row, int chunk) {
    return buf + (row << 7) + ((chunk ^ (row & 15)) << 3);
}
__device__ __forceinline__ short* sa_ptr(short* buf, int row, int chunk) {
    return buf + (row << 6) + ((chunk ^ (row & 7)) << 3);    // row stride 64 shorts
}
__device__ __forceinline__ const short* sa_ptr(const short* buf, int row, int chunk) {
    return buf + (row << 6) + ((chunk ^ (row & 7)) << 3);
}

template<bool ACT>
__device__ __forceinline__ void epi_store(short* chunk_base, int half, float4_ a) {
    float e0, e1, e2, e3;
    if (ACT) { e0 = elu_med3(a[0]); e1 = elu_med3(a[1]); e2 = elu_med3(a[2]); e3 = elu_med3(a[3]); }
    else { e0 = a[0]; e1 = a[1]; e2 = a[2]; e3 = a[3]; }
    uint2 p; p.x = pkbf(e0, e1); p.y = pkbf(e2, e3);
    *(uint2*)(chunk_base + half * 4) = p;
}

// =====================================================================
// Kernel 1: prep = pack_weights (blocks 0..291) + z_prez (blocks 292..)
// =====================================================================
__global__ void prep(const float* __restrict__ Wx0, const float* __restrict__ Wx,
                     const float* __restrict__ Wlx, const float* __restrict__ Wu0,
                     const float* __restrict__ Wu, const float* __restrict__ Wlast,
                     const float* __restrict__ Z, const float* __restrict__ Wz0,
                     const float* __restrict__ Wz, const float* __restrict__ Wlz,
                     short* __restrict__ pk, float* __restrict__ preZ)
{
    __shared__ float sZ[4][DZF], sH0[4][64], sH1[4][64], sZj[4][LZD];
    const int tid = threadIdx.x;

    if (blockIdx.x < NB_PACK) {
        int idx = blockIdx.x * 256 + tid;
        float v;
        if (idx < PK_WX) {
            int m = idx / 2048, r = idx % 2048, n = r / 32, k = r % 32;
            v = Wx0[m * 2048 + k * 64 + n];
        } else if (idx < PK_WLX2) {
            int t = idx - PK_WX; int m = t / 4096, r = t % 4096, n = r / 64, k = r % 64;
            v = Wx[m * 4096 + k * 64 + n];
        } else if (idx < PK_WU0) {
            int r = idx - PK_WLX2; int n = r / 64, k = r % 64;
            v = Wlx[2 * 1024 + k * 16 + n];
        } else if (idx < PK_WU) {
            int r = idx - PK_WU0; int n = r / 64, k = r % 64;
            v = (k < 48) ? Wu0[k * 128 + n] : 0.0f;
        } else if (idx < PK_WLAST) {
            int t = idx - PK_WU; int m = t / 16384, r = t % 16384, n = r / 128, k = r % 128;
            v = Wu[m * 16384 + k * 128 + n];
        } else {
            int r = idx - PK_WLAST; int n = r / 128, k = r % 128;
            v = (n == 0) ? Wlast[k] : 0.0f;
        }
        pk[idx] = f2bf(v);
        return;
    }

    // ---- z_prez path: 4 customers x 64 cols ----
    const int cu = tid >> 6, col = tid & 63;
    const int b0 = (blockIdx.x - NB_PACK) * 4;
    if (tid < 80) sZ[tid / DZF][tid % DZF] = Z[(size_t)(b0 + tid / DZF) * DZF + tid % DZF];
    __syncthreads();
    for (int j = 0; j < 3; ++j) {
        { const float* w = Wz0 + j * (DZF * 64);
          float s0 = 0.f, s1 = 0.f;
          for (int k = 0; k < DZF; k += 2) {
              s0 = fmaf(sZ[cu][k], w[k * 64 + col], s0);
              s1 = fmaf(sZ[cu][k + 1], w[(k + 1) * 64 + col], s1);
          }
          sH0[cu][col] = elu_fast(s0 + s1); }
        __syncthreads();
        { const float* w = Wz + (j * 2 + 0) * 4096;
          float s0 = 0.f, s1 = 0.f;
          for (int k = 0; k < 64; k += 2) {
              s0 = fmaf(sH0[cu][k], w[k * 64 + col], s0);
              s1 = fmaf(sH0[cu][k + 1], w[(k + 1) * 64 + col], s1);
          }
          sH1[cu][col] = elu_fast(s0 + s1); }
        __syncthreads();
        { const float* w = Wz + (j * 2 + 1) * 4096;
          float s0 = 0.f, s1 = 0.f;
          for (int k = 0; k < 64; k += 2) {
              s0 = fmaf(sH1[cu][k], w[k * 64 + col], s0);
              s1 = fmaf(sH1[cu][k + 1], w[(k + 1) * 64 + col], s1);
          }
          sH0[cu][col] = elu_fast(s0 + s1); }
        __syncthreads();
        if (col < LZD) {
            const float* w = Wlz + j * (64 * LZD);
            float s0 = 0.f, s1 = 0.f;
            for (int k = 0; k < 64; k += 2) {
                s0 = fmaf(sH0[cu][k], w[k * LZD + col], s0);
                s1 = fmaf(sH0[cu][k + 1], w[(k + 1) * LZD + col], s1);
            }
            sZj[cu][col] = s0 + s1;
        }
        __syncthreads();
        for (int half = 0; half < 2; ++half) {
            const int c = col + half * 64;
            float s = 0.f;
            for (int k = 0; k < LZD; ++k) s = fmaf(sZj[cu][k], Wu0[(48 + k) * WUW + c], s);
            for (int k = 0; k < DZF; ++k) s = fmaf(sZ[cu][k], Wu0[(64 + k) * WUW + c], s);
            preZ[((size_t)(b0 + cu) * 3 + j) * WUW + c] = s;
        }
        __syncthreads();
    }
}

// =====================================================================
// Kernel 2: fused x-branch + utility. One customer per block.
// Single sU buffer (read-all -> barrier -> write-back), swizzled LDS.
// LDS = 8K(sA0) + 16K(sU) + 1.5K(preZ) + 0.25K = 25.8 KB -> ~6 blocks/CU
// =====================================================================
__global__ __launch_bounds__(256, 4) void rum_main(
    const float* __restrict__ X, const short* __restrict__ pk,
    const float* __restrict__ preZ, float* __restrict__ out)
{
    __shared__ __align__(16) short sA0[64 * 64];    // [row=prod][k]: 0..31 X, 32..47 Xi, 48..63 zero
    __shared__ __align__(16) short sU[64 * 128];    // [row=prod][ch], swizzled
    __shared__ __align__(16) float sPreZ[3 * 128];
    __shared__ float sScore[64];

    const int tid = threadIdx.x;
    const int w = tid >> 6, lane = tid & 63;
    const int quad = lane >> 4, l15 = lane & 15;
    const long b = blockIdx.x;
    const short8 zero8 = (short8)0;

    // zero chunks 6,7 (k 48..63) rows 0..49, and ALL chunks of dead rows 50..63
    for (int idx = tid; idx < 100; idx += 256) {
        int r = idx >> 1, ch = 6 + (idx & 1);
        *(short8*)sa_ptr(sA0, r, ch) = zero8;
    }
    for (int idx = tid; idx < 112; idx += 256) {
        int r = 50 + (idx >> 3), ch = idx & 7;
        *(short8*)sa_ptr(sA0, r, ch) = zero8;
    }
    // stage X (50x32 fp32 -> bf16)
    for (int it = tid; it < 400; it += 256) {
        int r = it >> 3, c4 = it & 7;
        float4_ xv = *(const float4_*)(X + (b * 50 + r) * 32 + c4 * 4);
        uint2 p; p.x = pkbf(xv[0], xv[1]); p.y = pkbf(xv[2], xv[3]);
        *(uint2*)(sa_ptr(sA0, r, c4 >> 1) + (c4 & 1) * 4) = p;
    }
    if (tid < 96)
        *(float4_*)(sPreZ + tid * 4) = *(const float4_*)(preZ + b * 384 + tid * 4);
    __syncthreads();

    float accv = 0.f;
    const float inv_norm = 1.0f / (1.0f + 1e-6f * (float)NPROD);

    for (int i = 0; i < 3; ++i) {
        // ---- x l0: Wx0_i[64][32] @ A0^T -> sU (K=32) ----
        {
            const short* A = pk + PK_WX0 + i * 2048;
            short8 af = *(const short8*)(A + (w * 16 + l15) * 32 + quad * 8);
            #pragma unroll
            for (int pt = 0; pt < 4; ++pt) {
                short8 bfr = *(const short8*)sa_ptr(sA0, pt * 16 + l15, quad);
                float4_ acc = MFMA16(af, bfr, (float4_)0.f);
                epi_store<true>(su_ptr(sU, pt * 16 + l15, 2 * w + (quad >> 1)), quad & 1, acc);
            }
        }
        __syncthreads();

        // ---- x l1, l2: Wx[2i+l][64][64], sU -> sU ----
        for (int l = 0; l < 2; ++l) {
            const short* A = pk + PK_WX + (i * 2 + l) * 4096;
            short8 af0 = *(const short8*)(A + (w * 16 + l15) * 64 + quad * 8);
            short8 af1 = *(const short8*)(A + (w * 16 + l15) * 64 + 32 + quad * 8);
            float4_ ax[4];
            #pragma unroll
            for (int pt = 0; pt < 4; ++pt) {
                short8 b0 = *(const short8*)su_ptr(sU, pt * 16 + l15, quad);
                short8 b1 = *(const short8*)su_ptr(sU, pt * 16 + l15, 4 + quad);
                ax[pt] = MFMA16(af0, b0, (float4_)0.f);
                ax[pt] = MFMA16(af1, b1, ax[pt]);
            }
            __syncthreads();   // all reads done before overwrite
            #pragma unroll
            for (int pt = 0; pt < 4; ++pt)
                epi_store<true>(su_ptr(sU, pt * 16 + l15, 2 * w + (quad >> 1)), quad & 1, ax[pt]);
            __syncthreads();
        }

        // ---- x ll: Wlx[2][16][64], linear; write Xi -> sA0 chunks 4..5 ----
        {
            const short* A = pk + PK_WLX2;
            short8 af0 = *(const short8*)(A + l15 * 64 + quad * 8);
            short8 af1 = *(const short8*)(A + l15 * 64 + 32 + quad * 8);
            short8 b0 = *(const short8*)su_ptr(sU, w * 16 + l15, quad);
            short8 b1 = *(const short8*)su_ptr(sU, w * 16 + l15, 4 + quad);
            float4_ acc = MFMA16(af0, b0, (float4_)0.f);
            acc = MFMA16(af1, b1, acc);
            epi_store<false>(sa_ptr(sA0, w * 16 + l15, 4 + (quad >> 1)), quad & 1, acc);
        }
        __syncthreads();

        for (int j = 0; j < 3; ++j) {
            // ---- u0: Wu0p[128][64] @ A0^T -> sU, C init = preZ[j] ----
            {
                const short* A = pk + PK_WU0;
                short8 b0s[4], b1s[4];
                #pragma unroll
                for (int pt = 0; pt < 4; ++pt) {
                    b0s[pt] = *(const short8*)sa_ptr(sA0, pt * 16 + l15, quad);
                    b1s[pt] = *(const short8*)sa_ptr(sA0, pt * 16 + l15, 4 + quad);
                }
                #pragma unroll
                for (int wi = 0; wi < 2; ++wi) {
                    const int wt = w * 2 + wi;
                    float4_ pz = *(const float4_*)(sPreZ + j * 128 + wt * 16 + quad * 4);
                    short8 af0 = *(const short8*)(A + (wt * 16 + l15) * 64 + quad * 8);
                    short8 af1 = *(const short8*)(A + (wt * 16 + l15) * 64 + 32 + quad * 8);
                    #pragma unroll
                    for (int pt = 0; pt < 4; ++pt) {
                        float4_ t = MFMA16(af0, b0s[pt], pz);
                        t = MFMA16(af1, b1s[pt], t);
                        epi_store<true>(su_ptr(sU, pt * 16 + l15, 2 * wt + (quad >> 1)), quad & 1, t);
                    }
                }
            }
            __syncthreads();

            // ---- d1, d2: Wu[l][128][128], sU -> sU ----
            for (int l = 0; l < 2; ++l) {
                const short* A = pk + PK_WU + l * 16384;
                float4_ ad[2][4];
                #pragma unroll
                for (int wi = 0; wi < 2; ++wi)
                    #pragma unroll
                    for (int pt = 0; pt < 4; ++pt) ad[wi][pt] = (float4_)0.f;
                #pragma unroll
                for (int ks = 0; ks < 4; ++ks) {
                    short8 bf[4];
                    #pragma unroll
                    for (int pt = 0; pt < 4; ++pt)
                        bf[pt] = *(const short8*)su_ptr(sU, pt * 16 + l15, ks * 4 + quad);
                    #pragma unroll
                    for (int wi = 0; wi < 2; ++wi) {
                        short8 af = *(const short8*)(A + ((w * 2 + wi) * 16 + l15) * 128 + ks * 32 + quad * 8);
                        #pragma unroll
                        for (int pt = 0; pt < 4; ++pt)
                            ad[wi][pt] = MFMA16(af, bf[pt], ad[wi][pt]);
                    }
                }
                __syncthreads();   // reads complete
                #pragma unroll
                for (int wi = 0; wi < 2; ++wi)
                    #pragma unroll
                    for (int pt = 0; pt < 4; ++pt)
                        epi_store<true>(su_ptr(sU, pt * 16 + l15, 2 * (w * 2 + wi) + (quad >> 1)),
                                        quad & 1, ad[wi][pt]);
                __syncthreads();
            }

            // ---- score: pkWlast[16][128] @ u2^T; row 0 = score ----
            {
                const short* A = pk + PK_WLAST;
                float4_ as = (float4_)0.f;
                #pragma unroll
                for (int ks = 0; ks < 4; ++ks) {
                    short8 af = *(const short8*)(A + l15 * 128 + ks * 32 + quad * 8);
                    short8 bf = *(const short8*)su_ptr(sU, w * 16 + l15, ks * 4 + quad);
                    as = MFMA16(af, bf, as);
                }
                if (quad == 0) sScore[w * 16 + l15] = as[0];
            }
            __syncthreads();

            // ---- softmax (wave 0) ----
            if (tid < 64) {
                float sc = (tid < NPROD) ? sScore[tid] : -3.0e38f;
                float m = sc;
                #pragma unroll
                for (int off = 32; off > 0; off >>= 1) m = fmaxf(m, __shfl_xor(m, off));
                float e = (tid < NPROD) ? __builtin_amdgcn_exp2f((sc - m) * 1.44269504089f) : 0.f;
                float ssum = e;
                #pragma unroll
                for (int off = 32; off > 0; off >>= 1) ssum += __shfl_xor(ssum, off);
                if (tid < NPROD) accv += (1e-6f + e / ssum) * inv_norm;
            }
            __syncthreads();
        }
    }
    if (tid < NPROD) out[b * 50 + tid] = accv * (1.0f / 9.0f);
}

// =====================================================================
// Fallback (round-1 fp32 kernel, known-good) if ws too small
// =====================================================================
__device__ __forceinline__ float elu_f(float x) { return x > 0.0f ? x : expm1f(x); }
template<int IN, int OUT, bool ACT>
__device__ __forceinline__ void dense50(const float* __restrict__ in_lds,
                                        const float* __restrict__ Wg,
                                        float* __restrict__ out_lds)
{
    const int tid = threadIdx.x;
    constexpr int CQ = OUT / 4;
    const float4* __restrict__ W4 = (const float4*)Wg;
    for (int item = tid; item < 25 * CQ; item += 256) {
        const int rp = item / CQ, cq = item % CQ;
        const int r0 = rp, r1 = rp + 25;
        float4 a0 = {0,0,0,0}, a1 = {0,0,0,0};
        for (int k = 0; k < IN; ++k) {
            const float4 wv = W4[k * CQ + cq];
            const float x0 = in_lds[r0 * IN + k], x1 = in_lds[r1 * IN + k];
            a0.x = fmaf(x0, wv.x, a0.x); a0.y = fmaf(x0, wv.y, a0.y);
            a0.z = fmaf(x0, wv.z, a0.z); a0.w = fmaf(x0, wv.w, a0.w);
            a1.x = fmaf(x1, wv.x, a1.x); a1.y = fmaf(x1, wv.y, a1.y);
            a1.z = fmaf(x1, wv.z, a1.z); a1.w = fmaf(x1, wv.w, a1.w);
        }
        if (ACT) {
            a0.x = elu_f(a0.x); a0.y = elu_f(a0.y); a0.z = elu_f(a0.z); a0.w = elu_f(a0.w);
            a1.x = elu_f(a1.x); a1.y = elu_f(a1.y); a1.z = elu_f(a1.z); a1.w = elu_f(a1.w);
        }
        ((float4*)out_lds)[r0 * CQ + cq] = a0;
        ((float4*)out_lds)[r1 * CQ + cq] = a1;
    }
}
template<bool ACT>
__device__ __forceinline__ void dense128fb(const float* __restrict__ in_lds,
                                           const float* __restrict__ Wg,
                                           float* __restrict__ out_lds)
{
    const int tid = threadIdx.x;
    const float4* __restrict__ W4 = (const float4*)Wg;
    for (int item = tid; item < 13 * 32; item += 256) {
        const int rg = item >> 5, cq = item & 31;
        int r[4];
        #pragma unroll
        for (int t = 0; t < 4; ++t) r[t] = min(rg * 4 + t, NPROD - 1);
        float4 a[4];
        #pragma unroll
        for (int t = 0; t < 4; ++t) a[t] = make_float4(0, 0, 0, 0);
        for (int k = 0; k < 128; ++k) {
            const float4 wv = W4[k * 32 + cq];
            #pragma unroll
            for (int t = 0; t < 4; ++t) {
                const float x = in_lds[r[t] * 128 + k];
                a[t].x = fmaf(x, wv.x, a[t].x); a[t].y = fmaf(x, wv.y, a[t].y);
                a[t].z = fmaf(x, wv.z, a[t].z); a[t].w = fmaf(x, wv.w, a[t].w);
            }
        }
        #pragma unroll
        for (int t = 0; t < 4; ++t) {
            const int row = rg * 4 + t;
            if (row < NPROD) {
                float4 o = a[t];
                if (ACT) { o.x = elu_f(o.x); o.y = elu_f(o.y); o.z = elu_f(o.z); o.w = elu_f(o.w); }
                ((float4*)out_lds)[row * 32 + cq] = o;
            }
        }
    }
}
__device__ __forceinline__ void dense_u0fb(const float* __restrict__ sXb,
                                           const float* __restrict__ sXi,
                                           const float* __restrict__ preZ_j,
                                           const float* __restrict__ Wu0,
                                           float* __restrict__ out_lds)
{
    const int tid = threadIdx.x;
    const float4* __restrict__ W4 = (const float4*)Wu0;
    const float4* __restrict__ PZ4 = (const float4*)preZ_j;
    for (int item = tid; item < 13 * 32; item += 256) {
        const int rg = item >> 5, cq = item & 31;
        int r[4];
        #pragma unroll
        for (int t = 0; t < 4; ++t) r[t] = min(rg * 4 + t, NPROD - 1);
        const float4 pz = PZ4[cq];
        float4 a[4];
        #pragma unroll
        for (int t = 0; t < 4; ++t) a[t] = pz;
        for (int k = 0; k < DXF; ++k) {
            const float4 wv = W4[k * 32 + cq];
            #pragma unroll
            for (int t = 0; t < 4; ++t) {
                const float x = sXb[r[t] * DXF + k];
                a[t].x = fmaf(x, wv.x, a[t].x); a[t].y = fmaf(x, wv.y, a[t].y);
                a[t].z = fmaf(x, wv.z, a[t].z); a[t].w = fmaf(x, wv.w, a[t].w);
            }
        }
        for (int k = 0; k < LXD; ++k) {
            const float4 wv = W4[(DXF + k) * 32 + cq];
            #pragma unroll
            for (int t = 0; t < 4; ++t) {
                const float x = sXi[r[t] * LXD + k];
                a[t].x = fmaf(x, wv.x, a[t].x); a[t].y = fmaf(x, wv.y, a[t].y);
                a[t].z = fmaf(x, wv.z, a[t].z); a[t].w = fmaf(x, wv.w, a[t].w);
            }
        }
        #pragma unroll
        for (int t = 0; t < 4; ++t) {
            const int row = rg * 4 + t;
            if (row < NPROD) {
                float4 o = a[t];
                o.x = elu_f(o.x); o.y = elu_f(o.y); o.z = elu_f(o.z); o.w = elu_f(o.w);
                ((float4*)out_lds)[row * 32 + cq] = o;
            }
        }
    }
}
__global__ __launch_bounds__(256, 2) void rum_fused_fb(
    const float* __restrict__ X, const float* __restrict__ Z,
    const float* __restrict__ Wx0, const float* __restrict__ Wx,
    const float* __restrict__ Wlx, const float* __restrict__ Wz0,
    const float* __restrict__ Wz, const float* __restrict__ Wlz,
    const float* __restrict__ Wu0, const float* __restrict__ Wu,
    const float* __restrict__ Wlast, float* __restrict__ out)
{
    __shared__ __align__(16) float sBufA[NPROD * WUW];
    __shared__ __align__(16) float sBufB[NPROD * WUW];
    __shared__ __align__(16) float sXb[NPROD * DXF];
    __shared__ __align__(16) float sXi[NPROD * LXD];
    __shared__ __align__(16) float sPreZ[3 * WUW];
    const int b = blockIdx.x, tid = threadIdx.x;
    float* zsm = sBufA; float* zh0 = sBufA + 64; float* zh1 = sBufA + 256; float* zjd = sBufA + 448;
    {
        const float* Xg = X + (size_t)b * (NPROD * DXF);
        for (int idx = tid; idx < NPROD * DXF; idx += 256) sXb[idx] = Xg[idx];
        const float* Zg = Z + (size_t)b * DZF;
        if (tid < DZF) zsm[tid] = Zg[tid];
    }
    __syncthreads();
    const int zj = tid >> 6, zc = tid & 63;
    if (zj < 3) { const float* wv = Wz0 + zj * (DZF * 64); float s = 0;
        for (int k = 0; k < DZF; ++k) s = fmaf(zsm[k], wv[k * 64 + zc], s);
        zh0[zj * 64 + zc] = elu_f(s); }
    __syncthreads();
    if (zj < 3) { const float* wv = Wz + (zj * 2 + 0) * 4096; float s = 0;
        for (int k = 0; k < 64; ++k) s = fmaf(zh0[zj * 64 + k], wv[k * 64 + zc], s);
        zh1[zj * 64 + zc] = elu_f(s); }
    __syncthreads();
    if (zj < 3) { const float* wv = Wz + (zj * 2 + 1) * 4096; float s = 0;
        for (int k = 0; k < 64; ++k) s = fmaf(zh1[zj * 64 + k], wv[k * 64 + zc], s);
        zh0[zj * 64 + zc] = elu_f(s); }
    __syncthreads();
    if (tid < 48) { const int j = tid >> 4, c = tid & 15;
        const float* wv = Wlz + j * (64 * LZD); float s = 0;
        for (int k = 0; k < 64; ++k) s = fmaf(zh0[j * 64 + k], wv[k * LZD + c], s);
        zjd[j * LZD + c] = s; }
    __syncthreads();
    for (int idx = tid; idx < 3 * WUW; idx += 256) {
        const int j = idx >> 7, c = idx & 127; float s = 0;
        for (int k = 0; k < LZD; ++k) s = fmaf(zjd[j * LZD + k], Wu0[(DXF + LXD + k) * WUW + c], s);
        for (int k = 0; k < DZF; ++k) s = fmaf(zsm[k], Wu0[(DXF + LXD + LZD + k) * WUW + c], s);
        sPreZ[idx] = s;
    }
    __syncthreads();
    float accv = 0.f;
    const float inv_norm = 1.0f / (1.0f + 1e-6f * (float)NPROD);
    for (int i = 0; i < 3; ++i) {
        dense50<DXF, 64, true>(sXb, Wx0 + i * (DXF * 64), sBufA); __syncthreads();
        dense50<64, 64, true>(sBufA, Wx + (i * 2 + 0) * 4096, sBufB); __syncthreads();
        dense50<64, 64, true>(sBufB, Wx + (i * 2 + 1) * 4096, sBufA); __syncthreads();
        dense50<64, LXD, false>(sBufA, Wlx + 2 * (64 * LXD), sXi); __syncthreads();
        for (int j = 0; j < 3; ++j) {
            dense_u0fb(sXb, sXi, sPreZ + j * WUW, Wu0, sBufA); __syncthreads();
            dense128fb<true>(sBufA, Wu, sBufB); __syncthreads();
            dense128fb<true>(sBufB, Wu + 16384, sBufA); __syncthreads();
            if (tid < 64) {
                float sc = -3.0e38f;
                if (tid < NPROD) { float s = 0;
                    for (int k = 0; k < WUW; ++k) s = fmaf(sBufA[tid * WUW + k], Wlast[k], s);
                    sc = s; }
                float m = sc;
                #pragma unroll
                for (int off = 32; off > 0; off >>= 1) m = fmaxf(m, __shfl_xor(m, off));
                float e = (tid < NPROD) ? expf(sc - m) : 0.f;
                float ssum = e;
                #pragma unroll
                for (int off = 32; off > 0; off >>= 1) ssum += __shfl_xor(ssum, off);
                if (tid < NPROD) accv += (1e-6f + e / ssum) * inv_norm;
            }
            __syncthreads();
        }
    }
    if (tid < NPROD) out[(size_t)b * NPROD + tid] = accv * (1.0f / 9.0f);
}

// =====================================================================
extern "C" void kernel_launch(void* const* d_in, const int* in_sizes, int n_in,
                              void* d_out, int out_size, void* d_ws, size_t ws_size,
                              hipStream_t stream) {
    const float* X     = (const float*)d_in[0];
    const float* Z     = (const float*)d_in[1];
    const float* Wx0   = (const float*)d_in[2];
    const float* Wx    = (const float*)d_in[3];
    const float* Wlx   = (const float*)d_in[4];
    const float* Wz0   = (const float*)d_in[5];
    const float* Wz    = (const float*)d_in[6];
    const float* Wlz   = (const float*)d_in[7];
    const float* Wu0   = (const float*)d_in[8];
    const float* Wu    = (const float*)d_in[9];
    const float* Wlast = (const float*)d_in[10];
    float* out = (float*)d_out;

    if (ws_size < WS_NEEDED) {
        rum_fused_fb<<<dim3(8192), dim3(256), 0, stream>>>(
            X, Z, Wx0, Wx, Wlx, Wz0, Wz, Wlz, Wu0, Wu, Wlast, out);
        return;
    }

    char* wsB = (char*)d_ws;
    short* pk   = (short*)wsB;
    float* preZ = (float*)(wsB + PREZ_OFF_B);

    prep<<<dim3(NB_PACK + NB_Z), dim3(256), 0, stream>>>(
        Wx0, Wx, Wlx, Wu0, Wu, Wlast, Z, Wz0, Wz, Wlz, pk, preZ);
    rum_main<<<dim3(8192), dim3(256), 0, stream>>>(X, pk, preZ, out);
}

// Round 5
// 1198.038 us; speedup vs baseline: 28.9801x; 1.0548x over previous
//
#include <hip/hip_runtime.h>
#include <math.h>

#define NPROD 50
#define DXF 32
#define DZF 20
#define WUW 128
#define LXD 16
#define LZD 16

typedef __attribute__((ext_vector_type(8))) short short8;
typedef __attribute__((ext_vector_type(4))) float float4_;

__device__ __forceinline__ short f2bf(float x) {
    unsigned u = __builtin_bit_cast(unsigned, x);
    u += 0x7fffu + ((u >> 16) & 1u);
    return (short)(u >> 16);
}
__device__ __forceinline__ unsigned pkbf(float a, float b) {
#if __has_builtin(__builtin_amdgcn_cvt_pk_bf16_f32)
    auto v = __builtin_amdgcn_cvt_pk_bf16_f32(a, b);
    return __builtin_bit_cast(unsigned, v);
#else
    return (unsigned)(unsigned short)f2bf(a) | ((unsigned)(unsigned short)f2bf(b) << 16);
#endif
}
// elu(x) = med3(x, exp2(x*log2e)-1, 0)
__device__ __forceinline__ float elu_med3(float x) {
    float e = __builtin_amdgcn_exp2f(x * 1.44269504089f) - 1.0f;
#if __has_builtin(__builtin_amdgcn_fmed3f)
    return __builtin_amdgcn_fmed3f(x, e, 0.0f);
#else
    return x > 0.0f ? x : e;
#endif
}
__device__ __forceinline__ float elu_fast(float x) {
    float e = __builtin_amdgcn_exp2f(x * 1.44269504089f) - 1.0f;
    return x > 0.0f ? x : e;
}
#define MFMA16(a, b, c) __builtin_amdgcn_mfma_f32_16x16x32_bf16((a), (b), (c), 0, 0, 0)

// ---------------- ws layout ----------------
// All weights packed bf16, A-operand layout: pk[n*K + k] = W[k][n]
#define PK_WX0   0        // 3 x [64][32]
#define PK_WX    6144     // 6 x [64][64]
#define PK_WLX2  30720    // [16][64]   (leaked-k bug: Wlx[2] only)
#define PK_WU0   31744    // [128][64]  (k 0..31 X, 32..47 Xi, 48..63 zero)
#define PK_WU    39936    // 2 x [128][128]
#define PK_WLAST 72704    // [16][128]  (row 0 = Wlast, rest zero)
#define PK_TOTAL 74752
#define NB_PACK  292      // 74752/256 exactly
#define WS_NEEDED ((size_t)PK_TOTAL * 2)

// swizzled LDS addressing: 16B chunks XOR'd by row (<=2-way all phases)
__device__ __forceinline__ short* su_ptr(short* buf, int row, int chunk) {
    return buf + (row << 7) + ((chunk ^ (row & 15)) << 3);   // row stride 128 shorts
}
__device__ __forceinline__ const short* su_ptr(const short* buf, int row, int chunk) {
    return buf + (row << 7) + ((chunk ^ (row & 15)) << 3);
}
__device__ __forceinline__ short* sa_ptr(short* buf, int row, int chunk) {
    return buf + (row << 6) + ((chunk ^ (row & 7)) << 3);    // row stride 64 shorts
}
__device__ __forceinline__ const short* sa_ptr(const short* buf, int row, int chunk) {
    return buf + (row << 6) + ((chunk ^ (row & 7)) << 3);
}

template<bool ACT>
__device__ __forceinline__ void epi_store(short* chunk_base, int half, float4_ a) {
    float e0, e1, e2, e3;
    if (ACT) { e0 = elu_med3(a[0]); e1 = elu_med3(a[1]); e2 = elu_med3(a[2]); e3 = elu_med3(a[3]); }
    else { e0 = a[0]; e1 = a[1]; e2 = a[2]; e3 = a[3]; }
    uint2 p; p.x = pkbf(e0, e1); p.y = pkbf(e2, e3);
    *(uint2*)(chunk_base + half * 4) = p;
}

// =====================================================================
// Kernel 1: pack fp32 weights -> bf16 A-operand layout in ws
// =====================================================================
__global__ void pack_weights(const float* __restrict__ Wx0, const float* __restrict__ Wx,
                             const float* __restrict__ Wlx, const float* __restrict__ Wu0,
                             const float* __restrict__ Wu, const float* __restrict__ Wlast,
                             short* __restrict__ pk)
{
    int idx = blockIdx.x * 256 + threadIdx.x;
    if (idx >= PK_TOTAL) return;
    float v;
    if (idx < PK_WX) {
        int m = idx / 2048, r = idx % 2048, n = r / 32, k = r % 32;
        v = Wx0[m * 2048 + k * 64 + n];
    } else if (idx < PK_WLX2) {
        int t = idx - PK_WX; int m = t / 4096, r = t % 4096, n = r / 64, k = r % 64;
        v = Wx[m * 4096 + k * 64 + n];
    } else if (idx < PK_WU0) {
        int r = idx - PK_WLX2; int n = r / 64, k = r % 64;
        v = Wlx[2 * 1024 + k * 16 + n];
    } else if (idx < PK_WU) {
        int r = idx - PK_WU0; int n = r / 64, k = r % 64;
        v = (k < 48) ? Wu0[k * 128 + n] : 0.0f;
    } else if (idx < PK_WLAST) {
        int t = idx - PK_WU; int m = t / 16384, r = t % 16384, n = r / 128, k = r % 128;
        v = Wu[m * 16384 + k * 128 + n];
    } else {
        int r = idx - PK_WLAST; int n = r / 128, k = r % 128;
        v = (n == 0) ? Wlast[k] : 0.0f;
    }
    pk[idx] = f2bf(v);
}

// =====================================================================
// Kernel 2: everything else. One customer per block.
// Z-branch + preZ computed inline (waves 0..2, 123 FMA/thread).
// Single swizzled sU buffer; no big arch-VGPR staging (fits 64-arch at
// launch_bounds(256,4) without spills).
// =====================================================================
__global__ __launch_bounds__(256, 4) void rum_main(
    const float* __restrict__ X, const float* __restrict__ Z,
    const float* __restrict__ Wz0, const float* __restrict__ Wz,
    const float* __restrict__ Wlz, const float* __restrict__ Wu0,
    const short* __restrict__ pk, float* __restrict__ out)
{
    __shared__ __align__(16) short sA0[64 * 64];    // [prod][k]: 0..31 X, 32..47 Xi, 48..63 zero
    __shared__ __align__(16) short sU[64 * 128];    // [prod][ch], swizzled
    __shared__ __align__(16) float sPreZ[3 * 128];
    __shared__ float sScore[64];
    __shared__ float sZb[DZF];
    __shared__ float zA[3][64], zB[3][64];
    __shared__ float sZj[3][LZD];

    const int tid = threadIdx.x;
    const int w = tid >> 6, lane = tid & 63;
    const int quad = lane >> 4, l15 = lane & 15;
    const long b = blockIdx.x;
    const short8 zero8 = (short8)0;

    // zero chunks 6,7 (k 48..63) rows 0..49, and all chunks of rows 50..63
    for (int idx = tid; idx < 100; idx += 256) {
        int r = idx >> 1, ch = 6 + (idx & 1);
        *(short8*)sa_ptr(sA0, r, ch) = zero8;
    }
    if (tid < 112) {
        int r = 50 + (tid >> 3), ch = tid & 7;
        *(short8*)sa_ptr(sA0, r, ch) = zero8;
    }
    // stage X (50x32 fp32 -> bf16)
    for (int it = tid; it < 400; it += 256) {
        int r = it >> 3, c4 = it & 7;
        float4_ xv = *(const float4_*)(X + (b * 50 + r) * 32 + c4 * 4);
        uint2 p; p.x = pkbf(xv[0], xv[1]); p.y = pkbf(xv[2], xv[3]);
        *(uint2*)(sa_ptr(sA0, r, c4 >> 1) + (c4 & 1) * 4) = p;
    }
    if (tid < DZF) sZb[tid] = Z[b * DZF + tid];
    __syncthreads();

    // ---- inline Z-branch: wave w handles heterogeneity j=w ----
    if (w < 3) {
        const float* wv = Wz0 + w * (DZF * 64);
        float s0 = 0.f, s1 = 0.f;
        #pragma unroll
        for (int k = 0; k < DZF; k += 2) {
            s0 = fmaf(sZb[k], wv[k * 64 + lane], s0);
            s1 = fmaf(sZb[k + 1], wv[(k + 1) * 64 + lane], s1);
        }
        zA[w][lane] = elu_fast(s0 + s1);
    }
    __syncthreads();
    if (w < 3) {
        const float* wv = Wz + (w * 2 + 0) * 4096;
        float s0 = 0.f, s1 = 0.f;
        #pragma unroll
        for (int k = 0; k < 64; k += 2) {
            s0 = fmaf(zA[w][k], wv[k * 64 + lane], s0);
            s1 = fmaf(zA[w][k + 1], wv[(k + 1) * 64 + lane], s1);
        }
        zB[w][lane] = elu_fast(s0 + s1);
    }
    __syncthreads();
    if (w < 3) {
        const float* wv = Wz + (w * 2 + 1) * 4096;
        float s0 = 0.f, s1 = 0.f;
        #pragma unroll
        for (int k = 0; k < 64; k += 2) {
            s0 = fmaf(zB[w][k], wv[k * 64 + lane], s0);
            s1 = fmaf(zB[w][k + 1], wv[(k + 1) * 64 + lane], s1);
        }
        zA[w][lane] = elu_fast(s0 + s1);
    }
    __syncthreads();
    if (w < 3 && lane < LZD) {
        const float* wv = Wlz + w * (64 * LZD);
        float s0 = 0.f, s1 = 0.f;
        #pragma unroll
        for (int k = 0; k < 64; k += 2) {
            s0 = fmaf(zA[w][k], wv[k * LZD + lane], s0);
            s1 = fmaf(zA[w][k + 1], wv[(k + 1) * LZD + lane], s1);
        }
        sZj[w][lane] = s0 + s1;
    }
    __syncthreads();
    if (w < 3) {
        #pragma unroll
        for (int half = 0; half < 2; ++half) {
            const int c = lane + half * 64;
            float s = 0.f;
            #pragma unroll
            for (int k = 0; k < LZD; ++k) s = fmaf(sZj[w][k], Wu0[(48 + k) * WUW + c], s);
            #pragma unroll
            for (int k = 0; k < DZF; ++k) s = fmaf(sZb[k], Wu0[(64 + k) * WUW + c], s);
            sPreZ[w * 128 + c] = s;
        }
    }
    __syncthreads();

    float accv = 0.f;
    const float inv_norm = 1.0f / (1.0f + 1e-6f * (float)NPROD);

    for (int i = 0; i < 3; ++i) {
        // ---- x l0: Wx0_i[64][32] @ A0^T -> sU (K=32) ----
        {
            const short* A = pk + PK_WX0 + i * 2048;
            short8 af = *(const short8*)(A + (w * 16 + l15) * 32 + quad * 8);
            #pragma unroll
            for (int pt = 0; pt < 4; ++pt) {
                short8 bfr = *(const short8*)sa_ptr(sA0, pt * 16 + l15, quad);
                float4_ acc = MFMA16(af, bfr, (float4_)0.f);
                epi_store<true>(su_ptr(sU, pt * 16 + l15, 2 * w + (quad >> 1)), quad & 1, acc);
            }
        }
        __syncthreads();

        // ---- x l1, l2: Wx[2i+l][64][64], sU -> sU ----
        for (int l = 0; l < 2; ++l) {
            const short* A = pk + PK_WX + (i * 2 + l) * 4096;
            short8 af0 = *(const short8*)(A + (w * 16 + l15) * 64 + quad * 8);
            short8 af1 = *(const short8*)(A + (w * 16 + l15) * 64 + 32 + quad * 8);
            float4_ ax[4];
            #pragma unroll
            for (int pt = 0; pt < 4; ++pt) {
                short8 b0 = *(const short8*)su_ptr(sU, pt * 16 + l15, quad);
                short8 b1 = *(const short8*)su_ptr(sU, pt * 16 + l15, 4 + quad);
                ax[pt] = MFMA16(af0, b0, (float4_)0.f);
                ax[pt] = MFMA16(af1, b1, ax[pt]);
            }
            __syncthreads();
            #pragma unroll
            for (int pt = 0; pt < 4; ++pt)
                epi_store<true>(su_ptr(sU, pt * 16 + l15, 2 * w + (quad >> 1)), quad & 1, ax[pt]);
            __syncthreads();
        }

        // ---- x ll: Wlx[2][16][64], linear; Xi -> sA0 chunks 4..5 ----
        {
            const short* A = pk + PK_WLX2;
            short8 af0 = *(const short8*)(A + l15 * 64 + quad * 8);
            short8 af1 = *(const short8*)(A + l15 * 64 + 32 + quad * 8);
            short8 b0 = *(const short8*)su_ptr(sU, w * 16 + l15, quad);
            short8 b1 = *(const short8*)su_ptr(sU, w * 16 + l15, 4 + quad);
            float4_ acc = MFMA16(af0, b0, (float4_)0.f);
            acc = MFMA16(af1, b1, acc);
            epi_store<false>(sa_ptr(sA0, w * 16 + l15, 4 + (quad >> 1)), quad & 1, acc);
        }
        __syncthreads();

        for (int j = 0; j < 3; ++j) {
            // ---- u0: Wu0p[128][64] @ A0^T -> sU, C init = preZ[j] ----
            {
                const short* A = pk + PK_WU0;
                #pragma unroll
                for (int wi = 0; wi < 2; ++wi) {
                    const int wt = w * 2 + wi;
                    float4_ pz = *(const float4_*)(sPreZ + j * 128 + wt * 16 + quad * 4);
                    short8 af0 = *(const short8*)(A + (wt * 16 + l15) * 64 + quad * 8);
                    short8 af1 = *(const short8*)(A + (wt * 16 + l15) * 64 + 32 + quad * 8);
                    #pragma unroll
                    for (int pt = 0; pt < 4; ++pt) {
                        short8 b0 = *(const short8*)sa_ptr(sA0, pt * 16 + l15, quad);
                        short8 b1 = *(const short8*)sa_ptr(sA0, pt * 16 + l15, 4 + quad);
                        float4_ t = MFMA16(af0, b0, pz);
                        t = MFMA16(af1, b1, t);
                        epi_store<true>(su_ptr(sU, pt * 16 + l15, 2 * wt + (quad >> 1)), quad & 1, t);
                    }
                }
            }
            __syncthreads();

            // ---- d1, d2: Wu[l][128][128], sU -> sU ----
            for (int l = 0; l < 2; ++l) {
                const short* A = pk + PK_WU + l * 16384;
                float4_ ad[2][4];
                #pragma unroll
                for (int wi = 0; wi < 2; ++wi)
                    #pragma unroll
                    for (int pt = 0; pt < 4; ++pt) ad[wi][pt] = (float4_)0.f;
                #pragma unroll
                for (int ks = 0; ks < 4; ++ks) {
                    short8 bf[4];
                    #pragma unroll
                    for (int pt = 0; pt < 4; ++pt)
                        bf[pt] = *(const short8*)su_ptr(sU, pt * 16 + l15, ks * 4 + quad);
                    #pragma unroll
                    for (int wi = 0; wi < 2; ++wi) {
                        short8 af = *(const short8*)(A + ((w * 2 + wi) * 16 + l15) * 128 + ks * 32 + quad * 8);
                        #pragma unroll
                        for (int pt = 0; pt < 4; ++pt)
                            ad[wi][pt] = MFMA16(af, bf[pt], ad[wi][pt]);
                    }
                }
                __syncthreads();
                #pragma unroll
                for (int wi = 0; wi < 2; ++wi)
                    #pragma unroll
                    for (int pt = 0; pt < 4; ++pt)
                        epi_store<true>(su_ptr(sU, pt * 16 + l15, 2 * (w * 2 + wi) + (quad >> 1)),
                                        quad & 1, ad[wi][pt]);
                __syncthreads();
            }

            // ---- score: pkWlast[16][128] @ u2^T; row 0 = score ----
            {
                const short* A = pk + PK_WLAST;
                float4_ as = (float4_)0.f;
                #pragma unroll
                for (int ks = 0; ks < 4; ++ks) {
                    short8 af = *(const short8*)(A + l15 * 128 + ks * 32 + quad * 8);
                    short8 bf = *(const short8*)su_ptr(sU, w * 16 + l15, ks * 4 + quad);
                    as = MFMA16(af, bf, as);
                }
                if (quad == 0) sScore[w * 16 + l15] = as[0];
            }
            __syncthreads();

            // ---- softmax (wave 0) ----
            if (tid < 64) {
                float sc = (tid < NPROD) ? sScore[tid] : -3.0e38f;
                float m = sc;
                #pragma unroll
                for (int off = 32; off > 0; off >>= 1) m = fmaxf(m, __shfl_xor(m, off));
                float e = (tid < NPROD) ? __builtin_amdgcn_exp2f((sc - m) * 1.44269504089f) : 0.f;
                float ssum = e;
                #pragma unroll
                for (int off = 32; off > 0; off >>= 1) ssum += __shfl_xor(ssum, off);
                if (tid < NPROD) accv += (1e-6f + e / ssum) * inv_norm;
            }
            __syncthreads();
        }
    }
    if (tid < NPROD) out[b * 50 + tid] = accv * (1.0f / 9.0f);
}

// =====================================================================
// Fallback (round-1 fp32 kernel, known-good) if ws too small
// =====================================================================
__device__ __forceinline__ float elu_f(float x) { return x > 0.0f ? x : expm1f(x); }
template<int IN, int OUT, bool ACT>
__device__ __forceinline__ void dense50(const float* __restrict__ in_lds,
                                        const float* __restrict__ Wg,
                                        float* __restrict__ out_lds)
{
    const int tid = threadIdx.x;
    constexpr int CQ = OUT / 4;
    const float4* __restrict__ W4 = (const float4*)Wg;
    for (int item = tid; item < 25 * CQ; item += 256) {
        const int rp = item / CQ, cq = item % CQ;
        const int r0 = rp, r1 = rp + 25;
        float4 a0 = {0,0,0,0}, a1 = {0,0,0,0};
        for (int k = 0; k < IN; ++k) {
            const float4 wv = W4[k * CQ + cq];
            const float x0 = in_lds[r0 * IN + k], x1 = in_lds[r1 * IN + k];
            a0.x = fmaf(x0, wv.x, a0.x); a0.y = fmaf(x0, wv.y, a0.y);
            a0.z = fmaf(x0, wv.z, a0.z); a0.w = fmaf(x0, wv.w, a0.w);
            a1.x = fmaf(x1, wv.x, a1.x); a1.y = fmaf(x1, wv.y, a1.y);
            a1.z = fmaf(x1, wv.z, a1.z); a1.w = fmaf(x1, wv.w, a1.w);
        }
        if (ACT) {
            a0.x = elu_f(a0.x); a0.y = elu_f(a0.y); a0.z = elu_f(a0.z); a0.w = elu_f(a0.w);
            a1.x = elu_f(a1.x); a1.y = elu_f(a1.y); a1.z = elu_f(a1.z); a1.w = elu_f(a1.w);
        }
        ((float4*)out_lds)[r0 * CQ + cq] = a0;
        ((float4*)out_lds)[r1 * CQ + cq] = a1;
    }
}
template<bool ACT>
__device__ __forceinline__ void dense128fb(const float* __restrict__ in_lds,
                                           const float* __restrict__ Wg,
                                           float* __restrict__ out_lds)
{
    const int tid = threadIdx.x;
    const float4* __restrict__ W4 = (const float4*)Wg;
    for (int item = tid; item < 13 * 32; item += 256) {
        const int rg = item >> 5, cq = item & 31;
        int r[4];
        #pragma unroll
        for (int t = 0; t < 4; ++t) r[t] = min(rg * 4 + t, NPROD - 1);
        float4 a[4];
        #pragma unroll
        for (int t = 0; t < 4; ++t) a[t] = make_float4(0, 0, 0, 0);
        for (int k = 0; k < 128; ++k) {
            const float4 wv = W4[k * 32 + cq];
            #pragma unroll
            for (int t = 0; t < 4; ++t) {
                const float x = in_lds[r[t] * 128 + k];
                a[t].x = fmaf(x, wv.x, a[t].x); a[t].y = fmaf(x, wv.y, a[t].y);
                a[t].z = fmaf(x, wv.z, a[t].z); a[t].w = fmaf(x, wv.w, a[t].w);
            }
        }
        #pragma unroll
        for (int t = 0; t < 4; ++t) {
            const int row = rg * 4 + t;
            if (row < NPROD) {
                float4 o = a[t];
                if (ACT) { o.x = elu_f(o.x); o.y = elu_f(o.y); o.z = elu_f(o.z); o.w = elu_f(o.w); }
                ((float4*)out_lds)[row * 32 + cq] = o;
            }
        }
    }
}
__device__ __forceinline__ void dense_u0fb(const float* __restrict__ sXb,
                                           const float* __restrict__ sXi,
                                           const float* __restrict__ preZ_j,
                                           const float* __restrict__ Wu0,
                                           float* __restrict__ out_lds)
{
    const int tid = threadIdx.x;
    const float4* __restrict__ W4 = (const float4*)Wu0;
    const float4* __restrict__ PZ4 = (const float4*)preZ_j;
    for (int item = tid; item < 13 * 32; item += 256) {
        const int rg = item >> 5, cq = item & 31;
        int r[4];
        #pragma unroll
        for (int t = 0; t < 4; ++t) r[t] = min(rg * 4 + t, NPROD - 1);
        const float4 pz = PZ4[cq];
        float4 a[4];
        #pragma unroll
        for (int t = 0; t < 4; ++t) a[t] = pz;
        for (int k = 0; k < DXF; ++k) {
            const float4 wv = W4[k * 32 + cq];
            #pragma unroll
            for (int t = 0; t < 4; ++t) {
                const float x = sXb[r[t] * DXF + k];
                a[t].x = fmaf(x, wv.x, a[t].x); a[t].y = fmaf(x, wv.y, a[t].y);
                a[t].z = fmaf(x, wv.z, a[t].z); a[t].w = fmaf(x, wv.w, a[t].w);
            }
        }
        for (int k = 0; k < LXD; ++k) {
            const float4 wv = W4[(DXF + k) * 32 + cq];
            #pragma unroll
            for (int t = 0; t < 4; ++t) {
                const float x = sXi[r[t] * LXD + k];
                a[t].x = fmaf(x, wv.x, a[t].x); a[t].y = fmaf(x, wv.y, a[t].y);
                a[t].z = fmaf(x, wv.z, a[t].z); a[t].w = fmaf(x, wv.w, a[t].w);
            }
        }
        #pragma unroll
        for (int t = 0; t < 4; ++t) {
            const int row = rg * 4 + t;
            if (row < NPROD) {
                float4 o = a[t];
                o.x = elu_f(o.x); o.y = elu_f(o.y); o.z = elu_f(o.z); o.w = elu_f(o.w);
                ((float4*)out_lds)[row * 32 + cq] = o;
            }
        }
    }
}
__global__ __launch_bounds__(256, 2) void rum_fused_fb(
    const float* __restrict__ X, const float* __restrict__ Z,
    const float* __restrict__ Wx0, const float* __restrict__ Wx,
    const float* __restrict__ Wlx, const float* __restrict__ Wz0,
    const float* __restrict__ Wz, const float* __restrict__ Wlz,
    const float* __restrict__ Wu0, const float* __restrict__ Wu,
    const float* __restrict__ Wlast, float* __restrict__ out)
{
    __shared__ __align__(16) float sBufA[NPROD * WUW];
    __shared__ __align__(16) float sBufB[NPROD * WUW];
    __shared__ __align__(16) float sXb[NPROD * DXF];
    __shared__ __align__(16) float sXi[NPROD * LXD];
    __shared__ __align__(16) float sPreZ[3 * WUW];
    const int b = blockIdx.x, tid = threadIdx.x;
    float* zsm = sBufA; float* zh0 = sBufA + 64; float* zh1 = sBufA + 256; float* zjd = sBufA + 448;
    {
        const float* Xg = X + (size_t)b * (NPROD * DXF);
        for (int idx = tid; idx < NPROD * DXF; idx += 256) sXb[idx] = Xg[idx];
        const float* Zg = Z + (size_t)b * DZF;
        if (tid < DZF) zsm[tid] = Zg[tid];
    }
    __syncthreads();
    const int zj = tid >> 6, zc = tid & 63;
    if (zj < 3) { const float* wv = Wz0 + zj * (DZF * 64); float s = 0;
        for (int k = 0; k < DZF; ++k) s = fmaf(zsm[k], wv[k * 64 + zc], s);
        zh0[zj * 64 + zc] = elu_f(s); }
    __syncthreads();
    if (zj < 3) { const float* wv = Wz + (zj * 2 + 0) * 4096; float s = 0;
        for (int k = 0; k < 64; ++k) s = fmaf(zh0[zj * 64 + k], wv[k * 64 + zc], s);
        zh1[zj * 64 + zc] = elu_f(s); }
    __syncthreads();
    if (zj < 3) { const float* wv = Wz + (zj * 2 + 1) * 4096; float s = 0;
        for (int k = 0; k < 64; ++k) s = fmaf(zh1[zj * 64 + k], wv[k * 64 + zc], s);
        zh0[zj * 64 + zc] = elu_f(s); }
    __syncthreads();
    if (tid < 48) { const int j = tid >> 4, c = tid & 15;
        const float* wv = Wlz + j * (64 * LZD); float s = 0;
        for (int k = 0; k < 64; ++k) s = fmaf(zh0[j * 64 + k], wv[k * LZD + c], s);
        zjd[j * LZD + c] = s; }
    __syncthreads();
    for (int idx = tid; idx < 3 * WUW; idx += 256) {
        const int j = idx >> 7, c = idx & 127; float s = 0;
        for (int k = 0; k < LZD; ++k) s = fmaf(zjd[j * LZD + k], Wu0[(DXF + LXD + k) * WUW + c], s);
        for (int k = 0; k < DZF; ++k) s = fmaf(zsm[k], Wu0[(DXF + LXD + LZD + k) * WUW + c], s);
        sPreZ[idx] = s;
    }
    __syncthreads();
    float accv = 0.f;
    const float inv_norm = 1.0f / (1.0f + 1e-6f * (float)NPROD);
    for (int i = 0; i < 3; ++i) {
        dense50<DXF, 64, true>(sXb, Wx0 + i * (DXF * 64), sBufA); __syncthreads();
        dense50<64, 64, true>(sBufA, Wx + (i * 2 + 0) * 4096, sBufB); __syncthreads();
        dense50<64, 64, true>(sBufB, Wx + (i * 2 + 1) * 4096, sBufA); __syncthreads();
        dense50<64, LXD, false>(sBufA, Wlx + 2 * (64 * LXD), sXi); __syncthreads();
        for (int j = 0; j < 3; ++j) {
            dense_u0fb(sXb, sXi, sPreZ + j * WUW, Wu0, sBufA); __syncthreads();
            dense128fb<true>(sBufA, Wu, sBufB); __syncthreads();
            dense128fb<true>(sBufB, Wu + 16384, sBufA); __syncthreads();
            if (tid < 64) {
                float sc = -3.0e38f;
                if (tid < NPROD) { float s = 0;
                    for (int k = 0; k < WUW; ++k) s = fmaf(sBufA[tid * WUW + k], Wlast[k], s);
                    sc = s; }
                float m = sc;
                #pragma unroll
                for (int off = 32; off > 0; off >>= 1) m = fmaxf(m, __shfl_xor(m, off));
                float e = (tid < NPROD) ? expf(sc - m) : 0.f;
                float ssum = e;
                #pragma unroll
                for (int off = 32; off > 0; off >>= 1) ssum += __shfl_xor(ssum, off);
                if (tid < NPROD) accv += (1e-6f + e / ssum) * inv_norm;
            }
            __syncthreads();
        }
    }
    if (tid < NPROD) out[(size_t)b * NPROD + tid] = accv * (1.0f / 9.0f);
}

// =====================================================================
extern "C" void kernel_launch(void* const* d_in, const int* in_sizes, int n_in,
                              void* d_out, int out_size, void* d_ws, size_t ws_size,
                              hipStream_t stream) {
    const float* X     = (const float*)d_in[0];
    const float* Z     = (const float*)d_in[1];
    const float* Wx0   = (const float*)d_in[2];
    const float* Wx    = (const float*)d_in[3];
    const float* Wlx   = (const float*)d_in[4];
    const float* Wz0   = (const float*)d_in[5];
    const float* Wz    = (const float*)d_in[6];
    const float* Wlz   = (const float*)d_in[7];
    const float* Wu0   = (const float*)d_in[8];
    const float* Wu    = (const float*)d_in[9];
    const float* Wlast = (const float*)d_in[10];
    float* out = (float*)d_out;

    if (ws_size < WS_NEEDED) {
        rum_fused_fb<<<dim3(8192), dim3(256), 0, stream>>>(
            X, Z, Wx0, Wx, Wlx, Wz0, Wz, Wlz, Wu0, Wu, Wlast, out);
        return;
    }

    short* pk = (short*)d_ws;
    pack_weights<<<dim3(NB_PACK), dim3(256), 0, stream>>>(
        Wx0, Wx, Wlx, Wu0, Wu, Wlast, pk);
    rum_main<<<dim3(8192), dim3(256), 0, stream>>>(
        X, Z, Wz0, Wz, Wlz, Wu0, pk, out);
}